// Round 2
// baseline (1591.176 us; speedup 1.0000x reference)
//
#include <hip/hip_runtime.h>

#define S_ 4096
#define H_ 512
#define NH_ 8
#define HD_ 64
#define QKVLD 1536   // row stride of qkv buffer

// ============================================================================
// Generic fp32 GEMM: C[M,N] = A[M,K] @ W[K,N] + bias, optional ReLU.
// 128x128 tile, BK=16, 256 threads, 8x8 microtile (split 4+4 to avoid LDS
// bank conflicts), register double-buffered global loads.
// A staged transposed in LDS (As[k][m]); B staged natural (Bs[k][n]).
// ============================================================================
template<int RELU>
__global__ __launch_bounds__(256) void gemm_kernel(
    const float* __restrict__ A, int lda,
    const float* __restrict__ Wt, int ldw,
    const float* __restrict__ bias,
    float* __restrict__ C, int ldc,
    int M, int N, int K)
{
    __shared__ float As[16][132];   // A^T: As[k][m] (row stride 528B, 16B-aligned)
    __shared__ float Bs[16][132];   // natural: Bs[k][n]
    const int t  = threadIdx.x;
    const int tm = t >> 4, tn = t & 15;
    const int row0 = blockIdx.y * 128, col0 = blockIdx.x * 128;

    float acc[8][8];
    #pragma unroll
    for (int e = 0; e < 8; ++e)
        #pragma unroll
        for (int f = 0; f < 8; ++f) acc[e][f] = 0.f;

    float4 av[2], bv[2];
    // staging index map (512 float4 per tile each for A and B)
    const int ar  = (t + 0)   >> 2, ac4 = (t + 0)   & 3;    // i=0
    const int ar1 = (t + 256) >> 2, ac41 = (t + 256) & 3;   // i=1
    const int br  = (t + 0)   >> 5, bc4 = (t + 0)   & 31;
    const int br1 = (t + 256) >> 5, bc41 = (t + 256) & 31;

    // prologue: load tile 0
    av[0] = *(const float4*)(A + (size_t)(row0 + ar)  * lda + 0 + ac4  * 4);
    av[1] = *(const float4*)(A + (size_t)(row0 + ar1) * lda + 0 + ac41 * 4);
    bv[0] = *(const float4*)(Wt + (size_t)(0 + br)  * ldw + col0 + bc4  * 4);
    bv[1] = *(const float4*)(Wt + (size_t)(0 + br1) * ldw + col0 + bc41 * 4);

    for (int k0 = 0; ; ) {
        __syncthreads();   // prev tile's LDS readers done (no-op first iter)
        // store staged tile to LDS
        As[ac4  * 4 + 0][ar]  = av[0].x;
        As[ac4  * 4 + 1][ar]  = av[0].y;
        As[ac4  * 4 + 2][ar]  = av[0].z;
        As[ac4  * 4 + 3][ar]  = av[0].w;
        As[ac41 * 4 + 0][ar1] = av[1].x;
        As[ac41 * 4 + 1][ar1] = av[1].y;
        As[ac41 * 4 + 2][ar1] = av[1].z;
        As[ac41 * 4 + 3][ar1] = av[1].w;
        *(float4*)&Bs[br ][bc4  * 4] = bv[0];
        *(float4*)&Bs[br1][bc41 * 4] = bv[1];
        __syncthreads();

        const int k1 = k0 + 16;
        if (k1 < K) {   // issue next tile's loads; they overlap the FMA block
            av[0] = *(const float4*)(A + (size_t)(row0 + ar)  * lda + k1 + ac4  * 4);
            av[1] = *(const float4*)(A + (size_t)(row0 + ar1) * lda + k1 + ac41 * 4);
            bv[0] = *(const float4*)(Wt + (size_t)(k1 + br)  * ldw + col0 + bc4  * 4);
            bv[1] = *(const float4*)(Wt + (size_t)(k1 + br1) * ldw + col0 + bc41 * 4);
        }

        #pragma unroll
        for (int k = 0; k < 16; ++k) {
            float af[8], bf[8];
            *(float4*)&af[0] = *(const float4*)&As[k][tm * 4];        // rows tm*4..+3
            *(float4*)&af[4] = *(const float4*)&As[k][64 + tm * 4];   // rows 64+tm*4..+3
            *(float4*)&bf[0] = *(const float4*)&Bs[k][tn * 4];        // cols tn*4..+3
            *(float4*)&bf[4] = *(const float4*)&Bs[k][64 + tn * 4];   // cols 64+tn*4..+3
            #pragma unroll
            for (int e = 0; e < 8; ++e)
                #pragma unroll
                for (int f = 0; f < 8; ++f)
                    acc[e][f] = fmaf(af[e], bf[f], acc[e][f]);
        }
        if (k1 >= K) break;
        k0 = k1;
    }

    // epilogue: acc[e][f] -> row (eh*64 + tm*4 + e%4), col (fh*64 + tn*4 + f%4)
    #pragma unroll
    for (int eh = 0; eh < 2; ++eh) {
        #pragma unroll
        for (int e = 0; e < 4; ++e) {
            int r = row0 + eh * 64 + tm * 4 + e;
            #pragma unroll
            for (int fh = 0; fh < 2; ++fh) {
                int c = col0 + fh * 64 + tn * 4;
                float4 bb = *(const float4*)(bias + c);
                float4 o;
                o.x = acc[eh * 4 + e][fh * 4 + 0] + bb.x;
                o.y = acc[eh * 4 + e][fh * 4 + 1] + bb.y;
                o.z = acc[eh * 4 + e][fh * 4 + 2] + bb.z;
                o.w = acc[eh * 4 + e][fh * 4 + 3] + bb.w;
                if (RELU) {
                    o.x = fmaxf(o.x, 0.f); o.y = fmaxf(o.y, 0.f);
                    o.z = fmaxf(o.z, 0.f); o.w = fmaxf(o.w, 0.f);
                }
                *(float4*)(C + (size_t)r * ldc + c) = o;
            }
        }
    }
}

// ============================================================================
// Windowed (banded) MHA, flash-style. Block = (tile n of 64 queries, head h,
// batch b), 256 threads. Keys span [n*64-128, n*64+191] in 5 chunks of 64.
// Mask: |kpos-qpos|<=128 && kpos>=min_key && kpos<S.
// qkv layout [B,S,1536]: q=cols 0..511, k=512..1023, v=1024..1535 (+h*64).
// ============================================================================
__global__ __launch_bounds__(256) void wattn_kernel(
    const float* __restrict__ qkv,
    float* __restrict__ out,      // [B,S,512]
    int min_key)
{
    const int n = blockIdx.x, h = blockIdx.y, b = blockIdx.z;
    const int t = threadIdx.x;
    const int tm = t >> 4, tn = t & 15;

    __shared__ float Qs[64][68];  // natural [q][d], scaled by 1/8
    __shared__ float Kt[64][68];  // K^T [d][j], XOR-swizzled at 16B granularity
    __shared__ float Vs[64][68];  // natural [j][d]
    __shared__ float Ps[64][68];  // natural [q][j]

    const int q0g   = n * 64;
    const int kbase = q0g - 128;
    const size_t base = (size_t)b * S_ * QKVLD;

    // stage Q (pre-scaled by 1/sqrt(hd) = 0.125)
    #pragma unroll
    for (int i = 0; i < 4; ++i) {
        int idx = t + 256 * i;                 // 1024 float4
        int q = idx >> 4, c4 = idx & 15;
        float4 v = *(const float4*)(qkv + base + (size_t)(q0g + q) * QKVLD + h * 64 + c4 * 4);
        v.x *= 0.125f; v.y *= 0.125f; v.z *= 0.125f; v.w *= 0.125f;
        *(float4*)&Qs[q][c4 * 4] = v;
    }

    float m[4], l[4], o[4][4];
    #pragma unroll
    for (int e = 0; e < 4; ++e) {
        m[e] = -1e30f; l[e] = 0.f;
        #pragma unroll
        for (int g = 0; g < 4; ++g) o[e][g] = 0.f;
    }

    for (int c = 0; c < 5; ++c) {
        int klo = kbase + c * 64;
        if (klo >= S_ || klo + 63 < 0) continue;   // block-uniform skip
        __syncthreads();   // prev chunk's PV/score readers done (also makes Qs visible)

        // --- stage K transposed with XOR swizzle
        {
            int d = t & 63, w = t >> 6;
            #pragma unroll
            for (int i = 0; i < 4; ++i) {
                int jg = w + i * 4;            // key group 0..15
                float kv4[4];
                #pragma unroll
                for (int e2 = 0; e2 < 4; ++e2) {
                    int jp = klo + jg * 4 + e2;
                    kv4[e2] = (jp >= 0 && jp < S_)
                        ? qkv[base + (size_t)jp * QKVLD + 512 + h * 64 + d] : 0.f;
                }
                int c4s = jg ^ (d >> 3);
                *(float4*)&Kt[d][c4s * 4] = *(float4*)kv4;
            }
        }
        // --- stage V natural
        #pragma unroll
        for (int i = 0; i < 4; ++i) {
            int idx = t + 256 * i;
            int jj = idx >> 4, c4 = idx & 15;
            int jp = klo + jj;
            float4 v;
            if (jp >= 0 && jp < S_)
                v = *(const float4*)(qkv + base + (size_t)jp * QKVLD + 1024 + h * 64 + c4 * 4);
            else { v.x = 0.f; v.y = 0.f; v.z = 0.f; v.w = 0.f; }
            *(float4*)&Vs[jj][c4 * 4] = v;
        }
        __syncthreads();

        // --- scores: thread (tm,tn) -> queries 4tm..+3, keys 4tn..+3
        float s[4][4];
        #pragma unroll
        for (int e = 0; e < 4; ++e)
            #pragma unroll
            for (int f = 0; f < 4; ++f) s[e][f] = 0.f;
        #pragma unroll 8
        for (int d = 0; d < 64; ++d) {
            float a0 = Qs[4 * tm + 0][d], a1 = Qs[4 * tm + 1][d];
            float a2 = Qs[4 * tm + 2][d], a3 = Qs[4 * tm + 3][d];
            int c4s = tn ^ (d >> 3);
            float4 kf = *(const float4*)&Kt[d][c4s * 4];
            s[0][0] = fmaf(a0, kf.x, s[0][0]); s[0][1] = fmaf(a0, kf.y, s[0][1]);
            s[0][2] = fmaf(a0, kf.z, s[0][2]); s[0][3] = fmaf(a0, kf.w, s[0][3]);
            s[1][0] = fmaf(a1, kf.x, s[1][0]); s[1][1] = fmaf(a1, kf.y, s[1][1]);
            s[1][2] = fmaf(a1, kf.z, s[1][2]); s[1][3] = fmaf(a1, kf.w, s[1][3]);
            s[2][0] = fmaf(a2, kf.x, s[2][0]); s[2][1] = fmaf(a2, kf.y, s[2][1]);
            s[2][2] = fmaf(a2, kf.z, s[2][2]); s[2][3] = fmaf(a2, kf.w, s[2][3]);
            s[3][0] = fmaf(a3, kf.x, s[3][0]); s[3][1] = fmaf(a3, kf.y, s[3][1]);
            s[3][2] = fmaf(a3, kf.z, s[3][2]); s[3][3] = fmaf(a3, kf.w, s[3][3]);
        }
        // --- mask (positional, matches reference's where(..., NEG))
        #pragma unroll
        for (int e = 0; e < 4; ++e) {
            int qpos = q0g + 4 * tm + e;
            #pragma unroll
            for (int f = 0; f < 4; ++f) {
                int kpos = klo + 4 * tn + f;
                int rel = kpos - qpos;
                bool valid = (rel <= 128) & (rel >= -128) & (kpos >= min_key) & (kpos < S_);
                if (!valid) s[e][f] = -1e9f;
            }
        }
        // --- online softmax (row = 16 tn lanes, lane bits 0..3)
        #pragma unroll
        for (int e = 0; e < 4; ++e) {
            float mx = fmaxf(fmaxf(s[e][0], s[e][1]), fmaxf(s[e][2], s[e][3]));
            #pragma unroll
            for (int st = 1; st < 16; st <<= 1)
                mx = fmaxf(mx, __shfl_xor(mx, st, 64));
            float mn = fmaxf(m[e], mx);
            float sc = __expf(m[e] - mn);
            float ps = 0.f;
            #pragma unroll
            for (int f = 0; f < 4; ++f) { s[e][f] = __expf(s[e][f] - mn); ps += s[e][f]; }
            #pragma unroll
            for (int st = 1; st < 16; st <<= 1)
                ps += __shfl_xor(ps, st, 64);
            l[e] = l[e] * sc + ps;
            m[e] = mn;
            #pragma unroll
            for (int g = 0; g < 4; ++g) o[e][g] *= sc;
        }
        // --- write P to LDS, then PV
        #pragma unroll
        for (int e = 0; e < 4; ++e) {
            float4 pv; pv.x = s[e][0]; pv.y = s[e][1]; pv.z = s[e][2]; pv.w = s[e][3];
            *(float4*)&Ps[4 * tm + e][4 * tn] = pv;
        }
        __syncthreads();
        #pragma unroll 8
        for (int j = 0; j < 64; ++j) {
            float a0 = Ps[4 * tm + 0][j], a1 = Ps[4 * tm + 1][j];
            float a2 = Ps[4 * tm + 2][j], a3 = Ps[4 * tm + 3][j];
            float4 vf = *(const float4*)&Vs[j][4 * tn];
            o[0][0] = fmaf(a0, vf.x, o[0][0]); o[0][1] = fmaf(a0, vf.y, o[0][1]);
            o[0][2] = fmaf(a0, vf.z, o[0][2]); o[0][3] = fmaf(a0, vf.w, o[0][3]);
            o[1][0] = fmaf(a1, vf.x, o[1][0]); o[1][1] = fmaf(a1, vf.y, o[1][1]);
            o[1][2] = fmaf(a1, vf.z, o[1][2]); o[1][3] = fmaf(a1, vf.w, o[1][3]);
            o[2][0] = fmaf(a2, vf.x, o[2][0]); o[2][1] = fmaf(a2, vf.y, o[2][1]);
            o[2][2] = fmaf(a2, vf.z, o[2][2]); o[2][3] = fmaf(a2, vf.w, o[2][3]);
            o[3][0] = fmaf(a3, vf.x, o[3][0]); o[3][1] = fmaf(a3, vf.y, o[3][1]);
            o[3][2] = fmaf(a3, vf.z, o[3][2]); o[3][3] = fmaf(a3, vf.w, o[3][3]);
        }
    }
    // epilogue: normalize + store
    #pragma unroll
    for (int e = 0; e < 4; ++e) {
        float inv = 1.f / l[e];
        float4 ov;
        ov.x = o[e][0] * inv; ov.y = o[e][1] * inv;
        ov.z = o[e][2] * inv; ov.w = o[e][3] * inv;
        *(float4*)(out + ((size_t)b * S_ + q0g + 4 * tm + e) * H_ + h * 64 + 4 * tn) = ov;
    }
}

// ============================================================================
// cls-token query projection: q_cls[b,:] = x[b,0,:] @ Wq_cls + bq_cls
// ============================================================================
__global__ __launch_bounds__(256) void qcls_kernel(
    const float* __restrict__ x, const float* __restrict__ Wqkv,
    const float* __restrict__ bqkv, float* __restrict__ q_cls)
{
    __shared__ float sx[512];
    int idx = blockIdx.x * 256 + threadIdx.x;    // 1024 outputs
    int b = idx >> 9, j = idx & 511;
    for (int i = threadIdx.x; i < 512; i += 256) sx[i] = x[(size_t)b * S_ * H_ + i];
    __syncthreads();
    float s = bqkv[j];
    for (int d = 0; d < 512; ++d) s = fmaf(sx[d], Wqkv[(size_t)d * 1536 + j], s);
    q_cls[idx] = s;
}

// ============================================================================
// cls attention: per (b,h): softmax(q.k/8 over all S keys) @ v -> gpre[b,512]
// ============================================================================
__global__ __launch_bounds__(256) void cls_attn_kernel(
    const float* __restrict__ q_cls, const float* __restrict__ qkv,
    float* __restrict__ gpre)
{
    int b = blockIdx.x >> 3, h = blockIdx.x & 7;
    __shared__ float sQ[64];
    __shared__ float sS[S_];
    __shared__ float red[256];
    __shared__ float part[16][64];
    int t = threadIdx.x;
    if (t < 64) sQ[t] = q_cls[b * H_ + h * 64 + t] * 0.125f;
    __syncthreads();
    const size_t base = (size_t)b * S_ * QKVLD;
    float lmax = -1e30f;
    #pragma unroll 2
    for (int i = 0; i < 16; ++i) {
        int j = t + i * 256;
        const float* kr = qkv + base + (size_t)j * QKVLD + 512 + h * 64;
        float s = 0.f;
        #pragma unroll
        for (int d = 0; d < 64; d += 4) {
            float4 kv = *(const float4*)(kr + d);
            s = fmaf(sQ[d], kv.x, s); s = fmaf(sQ[d + 1], kv.y, s);
            s = fmaf(sQ[d + 2], kv.z, s); s = fmaf(sQ[d + 3], kv.w, s);
        }
        sS[j] = s;
        lmax = fmaxf(lmax, s);
    }
    red[t] = lmax; __syncthreads();
    for (int st = 128; st > 0; st >>= 1) {
        if (t < st) red[t] = fmaxf(red[t], red[t + st]);
        __syncthreads();
    }
    float mx = red[0];
    __syncthreads();
    float lsum = 0.f;
    #pragma unroll 2
    for (int i = 0; i < 16; ++i) {
        int j = t + i * 256;
        float p = __expf(sS[j] - mx);
        sS[j] = p;
        lsum += p;
    }
    red[t] = lsum; __syncthreads();
    for (int st = 128; st > 0; st >>= 1) {
        if (t < st) red[t] += red[t + st];
        __syncthreads();
    }
    float inv = 1.f / red[0];
    int g = t >> 4, d4 = t & 15;
    float4 acc; acc.x = 0.f; acc.y = 0.f; acc.z = 0.f; acc.w = 0.f;
    for (int j = g * 256; j < (g + 1) * 256; ++j) {
        float p = sS[j];
        float4 vv = *(const float4*)(qkv + base + (size_t)j * QKVLD + 1024 + h * 64 + d4 * 4);
        acc.x = fmaf(p, vv.x, acc.x); acc.y = fmaf(p, vv.y, acc.y);
        acc.z = fmaf(p, vv.z, acc.z); acc.w = fmaf(p, vv.w, acc.w);
    }
    *(float4*)&part[g][d4 * 4] = acc;
    __syncthreads();
    if (t < 64) {
        float r = 0.f;
        #pragma unroll
        for (int g2 = 0; g2 < 16; ++g2) r += part[g2][t];
        gpre[b * H_ + h * 64 + t] = r * inv;
    }
}

// ============================================================================
// cls output projection + LogN scaling, written into attended row (b,0,:)
// ============================================================================
__global__ __launch_bounds__(256) void clsproj_kernel(
    const float* __restrict__ gpre, const float* __restrict__ Wo,
    const float* __restrict__ bo, const float* __restrict__ logn,
    float* __restrict__ attended)
{
    __shared__ float sg[512];
    int idx = blockIdx.x * 256 + threadIdx.x;    // 1024 outputs
    int b = idx >> 9, j = idx & 511;
    for (int i = threadIdx.x; i < 512; i += 256) sg[i] = gpre[b * H_ + i];
    __syncthreads();
    float s = bo[j];
    for (int d = 0; d < 512; ++d) s = fmaf(sg[d], Wo[(size_t)d * H_ + j], s);
    attended[(size_t)b * S_ * H_ + j] = s * logn[0];
}

// ============================================================================
// classifier: out[r,l] = seq[r,:] @ Wc[:,l] + bc[l]   (L=17)
// ============================================================================
__global__ __launch_bounds__(256) void logits_kernel(
    const float* __restrict__ seq, const float* __restrict__ Wc,
    const float* __restrict__ bc, float* __restrict__ out)
{
    __shared__ float sWc[17][516];
    for (int i = threadIdx.x; i < 512 * 17; i += 256) {
        int d = i / 17, lcol = i % 17;
        sWc[lcol][d] = Wc[i];
    }
    __syncthreads();
    int idx = blockIdx.x * 256 + threadIdx.x;
    if (idx >= 8192 * 17) return;
    int r = idx / 17, lcol = idx % 17;
    const float* sr = seq + (size_t)r * H_;
    float s = bc[lcol];
    for (int d4 = 0; d4 < 128; ++d4) {
        float4 a = *(const float4*)(sr + d4 * 4);
        s = fmaf(a.x, sWc[lcol][d4 * 4 + 0], s);
        s = fmaf(a.y, sWc[lcol][d4 * 4 + 1], s);
        s = fmaf(a.z, sWc[lcol][d4 * 4 + 2], s);
        s = fmaf(a.w, sWc[lcol][d4 * 4 + 3], s);
    }
    out[idx] = s;
}

// ============================================================================
extern "C" void kernel_launch(void* const* d_in, const int* in_sizes, int n_in,
                              void* d_out, int out_size, void* d_ws, size_t ws_size,
                              hipStream_t stream) {
    const float* x        = (const float*)d_in[0];
    const float* Wqkv_cls = (const float*)d_in[1];
    const float* bqkv_cls = (const float*)d_in[2];
    const float* Wo_cls   = (const float*)d_in[3];
    const float* bo_cls   = (const float*)d_in[4];
    const float* Wqkv_loc = (const float*)d_in[5];
    const float* bqkv_loc = (const float*)d_in[6];
    const float* Wo_loc   = (const float*)d_in[7];
    const float* bo_loc   = (const float*)d_in[8];
    const float* logn     = (const float*)d_in[9];
    const float* Wqkv_h   = (const float*)d_in[10];
    const float* bqkv_h   = (const float*)d_in[11];
    const float* Wo_h     = (const float*)d_in[12];
    const float* bo_h     = (const float*)d_in[13];
    const float* Wqkv_v   = (const float*)d_in[14];
    const float* bqkv_v   = (const float*)d_in[15];
    const float* Wo_v     = (const float*)d_in[16];
    const float* bo_v     = (const float*)d_in[17];
    const float* W1       = (const float*)d_in[18];
    const float* b1       = (const float*)d_in[19];
    const float* W2       = (const float*)d_in[20];
    const float* b2       = (const float*)d_in[21];
    const float* Wc       = (const float*)d_in[22];
    const float* bc       = (const float*)d_in[23];
    float* out = (float*)d_out;

    // workspace layout (floats); total ~117 MB
    float* ws       = (float*)d_ws;
    float* qkv      = ws;                       // [B,S,1536]
    float* attnout  = ws + 12582912;            // [B,S,512]
    float* attended = ws + 16777216;            // [B,S,512]
    float* combined = ws + 20971520;            // [B,S,1024] = [h_out | v_out]
    float* q_cls    = ws + 29360128;            // [B,512]
    float* gpre     = ws + 29361152;            // [B,512]
    float* hidden   = attnout;                  // reuse after h/v attention done
    float* seq      = attended;                 // reuse after v-QKV GEMM done

    const int M = 2 * S_;   // 8192
    dim3 blk(256);

    // 1. cls K,V projection -> qkv cols 512..1535
    gemm_kernel<0><<<dim3(1024 / 128, M / 128), blk, 0, stream>>>(
        x, 512, Wqkv_cls + 512, 1536, bqkv_cls + 512, qkv + 512, 1536, M, 1024, 512);
    // 2. cls q projection
    qcls_kernel<<<dim3(4), blk, 0, stream>>>(x, Wqkv_cls, bqkv_cls, q_cls);
    // 3. cls attention
    cls_attn_kernel<<<dim3(16), blk, 0, stream>>>(q_cls, qkv, gpre);
    // 4. loc QKV
    gemm_kernel<0><<<dim3(1536 / 128, M / 128), blk, 0, stream>>>(
        x, 512, Wqkv_loc, 1536, bqkv_loc, qkv, 1536, M, 1536, 512);
    // 5. loc windowed attention (min_key=1)
    wattn_kernel<<<dim3(64, 8, 2), blk, 0, stream>>>(qkv, attnout, 1);
    // 6. loc output projection -> attended (all rows; row 0 fixed next)
    gemm_kernel<0><<<dim3(512 / 128, M / 128), blk, 0, stream>>>(
        attnout, 512, Wo_loc, 512, bo_loc, attended, 512, M, 512, 512);
    // 7. cls Wo + LogN -> attended rows (b,0)
    clsproj_kernel<<<dim3(4), blk, 0, stream>>>(gpre, Wo_cls, bo_cls, logn, attended);
    // 8. h QKV
    gemm_kernel<0><<<dim3(1536 / 128, M / 128), blk, 0, stream>>>(
        attended, 512, Wqkv_h, 1536, bqkv_h, qkv, 1536, M, 1536, 512);
    // 9. h windowed attention (min_key=0)
    wattn_kernel<<<dim3(64, 8, 2), blk, 0, stream>>>(qkv, attnout, 0);
    // 10. h output projection -> combined cols 0..511
    gemm_kernel<0><<<dim3(512 / 128, M / 128), blk, 0, stream>>>(
        attnout, 512, Wo_h, 512, bo_h, combined, 1024, M, 512, 512);
    // 11. v QKV
    gemm_kernel<0><<<dim3(1536 / 128, M / 128), blk, 0, stream>>>(
        attended, 512, Wqkv_v, 1536, bqkv_v, qkv, 1536, M, 1536, 512);
    // 12. v windowed attention
    wattn_kernel<<<dim3(64, 8, 2), blk, 0, stream>>>(qkv, attnout, 0);
    // 13. v output projection -> combined cols 512..1023
    gemm_kernel<0><<<dim3(512 / 128, M / 128), blk, 0, stream>>>(
        attnout, 512, Wo_v, 512, bo_v, combined + 512, 1024, M, 512, 512);
    // 14. MLP layer 1 (ReLU) -> hidden
    gemm_kernel<1><<<dim3(512 / 128, M / 128), blk, 0, stream>>>(
        combined, 1024, W1, 512, b1, hidden, 512, M, 512, 1024);
    // 15. MLP layer 2 -> seq
    gemm_kernel<0><<<dim3(512 / 128, M / 128), blk, 0, stream>>>(
        hidden, 512, W2, 512, b2, seq, 512, M, 512, 512);
    // 16. classifier -> d_out
    logits_kernel<<<dim3((M * 17 + 255) / 256), blk, 0, stream>>>(seq, Wc, bc, out);
}

// Round 6
// 783.319 us; speedup vs baseline: 2.0313x; 2.0313x over previous
//
#include <hip/hip_runtime.h>

#define S_ 4096
#define H_ 512
#define QKVLD 1536
#define M_ 8192

typedef __attribute__((ext_vector_type(8))) short s16x8;   // 8 bf16 = 4 VGPR
typedef __attribute__((ext_vector_type(4))) float f32x4;   // MFMA acc frag

__device__ __forceinline__ float bflo(unsigned int w) { return __uint_as_float(w << 16); }
__device__ __forceinline__ float bfhi(unsigned int w) { return __uint_as_float(w & 0xFFFF0000u); }
__device__ __forceinline__ float bf2f(unsigned short u) { return __uint_as_float(((unsigned int)u) << 16); }
__device__ __forceinline__ unsigned short f2bf(float f) {   // RNE
    unsigned int x = __float_as_uint(f);
    return (unsigned short)((x + 0x7FFFu + ((x >> 16) & 1u)) >> 16);
}
__device__ __forceinline__ void gload_lds16(const void* g, void* l) {
    __builtin_amdgcn_global_load_lds(
        (const __attribute__((address_space(1))) unsigned int*)g,
        (__attribute__((address_space(3))) unsigned int*)l, 16, 0, 0);
}

// ============================================================================
// fp32 -> bf16 cast (x input), 8 elts/thread.  n8 = total_elements / 8.
// x has B*S*H = 4,194,304 floats -> n8 = 524288 (Round-5 crash was n8=2x: OOB).
// ============================================================================
__global__ __launch_bounds__(256) void cvt_kernel(
    const float* __restrict__ in, unsigned short* __restrict__ out, int n8)
{
    int i = blockIdx.x * 256 + threadIdx.x;
    if (i >= n8) return;
    float4 a = *(const float4*)(in + (size_t)i * 8);
    float4 b = *(const float4*)(in + (size_t)i * 8 + 4);
    uint4 pk;
    pk.x = (unsigned int)f2bf(a.x) | ((unsigned int)f2bf(a.y) << 16);
    pk.y = (unsigned int)f2bf(a.z) | ((unsigned int)f2bf(a.w) << 16);
    pk.z = (unsigned int)f2bf(b.x) | ((unsigned int)f2bf(b.y) << 16);
    pk.w = (unsigned int)f2bf(b.z) | ((unsigned int)f2bf(b.w) << 16);
    *(uint4*)(out + (size_t)i * 8) = pk;
}

// ============================================================================
// Weight transpose + cast: in fp32 [K][N] -> out bf16 [N][K]; 4 matrices via z.
// ============================================================================
__global__ __launch_bounds__(256) void wtrans_kernel(
    const float* __restrict__ p0, const float* __restrict__ p1,
    const float* __restrict__ p2, const float* __restrict__ p3,
    unsigned short* o0, unsigned short* o1,
    unsigned short* o2, unsigned short* o3,
    int K, int N)
{
    const float* in; unsigned short* out;
    switch (blockIdx.z) {
        case 0:  in = p0; out = o0; break;
        case 1:  in = p1; out = o1; break;
        case 2:  in = p2; out = o2; break;
        default: in = p3; out = o3; break;
    }
    __shared__ float tile[32][33];
    int n0 = blockIdx.x * 32, k0 = blockIdx.y * 32;
    int tx = threadIdx.x & 31, ty = threadIdx.x >> 5;   // 32 x 8
    #pragma unroll
    for (int i = 0; i < 4; ++i) {
        int k = k0 + ty * 4 + i;
        tile[ty * 4 + i][tx] = in[(size_t)k * N + n0 + tx];
    }
    __syncthreads();
    #pragma unroll
    for (int i = 0; i < 4; ++i) {
        int n = n0 + ty * 4 + i;
        out[(size_t)n * K + k0 + tx] = f2bf(tile[tx][ty * 4 + i]);
    }
}

// ============================================================================
// bf16 MFMA GEMM: C[M,N] = A[M,K] @ B[K,N] + bias (B given transposed [N][K]).
// Tile BM x 128, BK=64, 256 threads = 4 waves (2x2), each wave (BM/2) x 64.
// Staging: global_load_lds width 16 with pre-swizzled global source so the
// linear LDS content matches the XOR-swizzled ds_read_b128 pattern (m173).
// Swizzle: k-chunk' = k-chunk ^ (row & 7)  (16B granularity) -> 2-way max.
// MFMA 16x16x32 bf16; C/D layout col=lane&15, row=(lane>>4)*4+reg (m89).
// Output written bf16.
// ============================================================================
template<int BM, int RELU>
__global__ __launch_bounds__(256) void mgemm_kernel(
    const unsigned short* __restrict__ A, int lda,
    const unsigned short* __restrict__ Bt, int ldb,
    const float* __restrict__ bias,
    unsigned short* __restrict__ C, int ldc, int K)
{
    constexpr int MF = BM / 32;          // m-frags per wave
    constexpr int ASEG = BM / 32;        // A 8-row segments per wave (BM/8/4)
    __shared__ __align__(16) unsigned short As[BM * 64];
    __shared__ __align__(16) unsigned short Bs[128 * 64];
    const int t = threadIdx.x;
    const int w = t >> 6, l = t & 63;
    const int wr = w >> 1, wc = w & 1;
    const int row0 = blockIdx.y * BM, col0 = blockIdx.x * 128;
    const int lr = l >> 3;               // row within 8-row segment
    const int lc = l & 7;                // 16B k-chunk within row

    f32x4 acc[MF][4];
    #pragma unroll
    for (int i = 0; i < MF; ++i)
        #pragma unroll
        for (int j = 0; j < 4; ++j) acc[i][j] = {0.f, 0.f, 0.f, 0.f};

    for (int k0 = 0; k0 < K; k0 += 64) {
        __syncthreads();   // prev iter's ds_reads done before overwrite
        #pragma unroll
        for (int i = 0; i < ASEG; ++i) {
            int seg = w * ASEG + i;
            int r = seg * 8 + lr;
            int kc = lc ^ (r & 7);       // pre-swizzled global source
            gload_lds16(A + (size_t)(row0 + r) * lda + k0 + kc * 8,
                        (void*)(As + seg * 512));
        }
        #pragma unroll
        for (int i = 0; i < 4; ++i) {
            int seg = w * 4 + i;
            int r = seg * 8 + lr;
            int kc = lc ^ (r & 7);
            gload_lds16(Bt + (size_t)(col0 + r) * ldb + k0 + kc * 8,
                        (void*)(Bs + seg * 512));
        }
        __syncthreads();   // compiler emits vmcnt(0) drain before barrier

        s16x8 af[MF][2], bf[4][2];
        #pragma unroll
        for (int mf = 0; mf < MF; ++mf)
            #pragma unroll
            for (int kk = 0; kk < 2; ++kk) {
                int r = wr * (BM / 2) + mf * 16 + (l & 15);
                int ch = (kk * 4 + (l >> 4)) ^ (r & 7);
                af[mf][kk] = *(const s16x8*)(As + r * 64 + ch * 8);
            }
        #pragma unroll
        for (int nf = 0; nf < 4; ++nf)
            #pragma unroll
            for (int kk = 0; kk < 2; ++kk) {
                int r = wc * 64 + nf * 16 + (l & 15);
                int ch = (kk * 4 + (l >> 4)) ^ (r & 7);
                bf[nf][kk] = *(const s16x8*)(Bs + r * 64 + ch * 8);
            }
        #pragma unroll
        for (int kk = 0; kk < 2; ++kk)
            #pragma unroll
            for (int mf = 0; mf < MF; ++mf)
                #pragma unroll
                for (int nf = 0; nf < 4; ++nf)
                    acc[mf][nf] = __builtin_amdgcn_mfma_f32_16x16x32_bf16(
                        af[mf][kk], bf[nf][kk], acc[mf][nf], 0, 0, 0);
    }

    #pragma unroll
    for (int mf = 0; mf < MF; ++mf)
        #pragma unroll
        for (int nf = 0; nf < 4; ++nf) {
            int col = col0 + wc * 64 + nf * 16 + (l & 15);
            float bb = bias[col];
            #pragma unroll
            for (int r4 = 0; r4 < 4; ++r4) {
                int row = row0 + wr * (BM / 2) + mf * 16 + (l >> 4) * 4 + r4;
                float v = acc[mf][nf][r4] + bb;
                if (RELU) v = fmaxf(v, 0.f);
                C[(size_t)row * ldc + col] = f2bf(v);
            }
        }
}

// ============================================================================
// Windowed (banded) MHA, flash-style, bf16 in / bf16 out, fp32 compute.
// Block = (64-query tile n, head h, batch b), 256 threads.
// ============================================================================
__global__ __launch_bounds__(256) void wattn_kernel(
    const unsigned short* __restrict__ qkv,
    unsigned short* __restrict__ out,      // [B,S,512] bf16
    int min_key)
{
    const int n = blockIdx.x, h = blockIdx.y, b = blockIdx.z;
    const int t = threadIdx.x;
    const int tm = t >> 4, tn = t & 15;

    __shared__ float Qs[64][68];
    __shared__ float Kt[64][68];  // K^T [d][j], 16B-XOR-swizzled
    __shared__ float Vs[64][68];
    __shared__ float Ps[64][68];

    const int q0g   = n * 64;
    const int kbase = q0g - 128;
    const size_t base = (size_t)b * S_ * QKVLD;

    // stage Q (scaled 1/8): 512 chunks of 8 bf16
    #pragma unroll
    for (int i = 0; i < 2; ++i) {
        int c = t + 256 * i;
        int q = c >> 3, c8 = c & 7;
        uint4 raw = *(const uint4*)(qkv + base + (size_t)(q0g + q) * QKVLD + h * 64 + c8 * 8);
        float* dq = &Qs[q][c8 * 8];
        dq[0] = bflo(raw.x) * 0.125f; dq[1] = bfhi(raw.x) * 0.125f;
        dq[2] = bflo(raw.y) * 0.125f; dq[3] = bfhi(raw.y) * 0.125f;
        dq[4] = bflo(raw.z) * 0.125f; dq[5] = bfhi(raw.z) * 0.125f;
        dq[6] = bflo(raw.w) * 0.125f; dq[7] = bfhi(raw.w) * 0.125f;
    }

    float m[4], lsum[4], o[4][4];
    #pragma unroll
    for (int e = 0; e < 4; ++e) {
        m[e] = -1e30f; lsum[e] = 0.f;
        #pragma unroll
        for (int g = 0; g < 4; ++g) o[e][g] = 0.f;
    }

    for (int c = 0; c < 5; ++c) {
        int klo = kbase + c * 64;
        if (klo >= S_ || klo + 63 < 0) continue;   // block-uniform
        __syncthreads();

        // stage K transposed (scalar bf16 gather) with XOR swizzle
        {
            int d = t & 63, w = t >> 6;
            #pragma unroll
            for (int i = 0; i < 4; ++i) {
                int jg = w + i * 4;
                float kv4[4];
                #pragma unroll
                for (int e2 = 0; e2 < 4; ++e2) {
                    int jp = klo + jg * 4 + e2;
                    kv4[e2] = (jp >= 0 && jp < S_)
                        ? bf2f(qkv[base + (size_t)jp * QKVLD + 512 + h * 64 + d]) : 0.f;
                }
                int c4s = jg ^ (d >> 3);
                *(float4*)&Kt[d][c4s * 4] = *(float4*)kv4;
            }
        }
        // stage V natural
        #pragma unroll
        for (int i = 0; i < 2; ++i) {
            int cc = t + 256 * i;
            int jj = cc >> 3, c8 = cc & 7;
            int jp = klo + jj;
            float* dv = &Vs[jj][c8 * 8];
            if (jp >= 0 && jp < S_) {
                uint4 raw = *(const uint4*)(qkv + base + (size_t)jp * QKVLD + 1024 + h * 64 + c8 * 8);
                dv[0] = bflo(raw.x); dv[1] = bfhi(raw.x);
                dv[2] = bflo(raw.y); dv[3] = bfhi(raw.y);
                dv[4] = bflo(raw.z); dv[5] = bfhi(raw.z);
                dv[6] = bflo(raw.w); dv[7] = bfhi(raw.w);
            } else {
                dv[0] = 0.f; dv[1] = 0.f; dv[2] = 0.f; dv[3] = 0.f;
                dv[4] = 0.f; dv[5] = 0.f; dv[6] = 0.f; dv[7] = 0.f;
            }
        }
        __syncthreads();

        // scores
        float s[4][4];
        #pragma unroll
        for (int e = 0; e < 4; ++e)
            #pragma unroll
            for (int f = 0; f < 4; ++f) s[e][f] = 0.f;
        #pragma unroll 8
        for (int d = 0; d < 64; ++d) {
            float a0 = Qs[4 * tm + 0][d], a1 = Qs[4 * tm + 1][d];
            float a2 = Qs[4 * tm + 2][d], a3 = Qs[4 * tm + 3][d];
            int c4s = tn ^ (d >> 3);
            float4 kf = *(const float4*)&Kt[d][c4s * 4];
            s[0][0] = fmaf(a0, kf.x, s[0][0]); s[0][1] = fmaf(a0, kf.y, s[0][1]);
            s[0][2] = fmaf(a0, kf.z, s[0][2]); s[0][3] = fmaf(a0, kf.w, s[0][3]);
            s[1][0] = fmaf(a1, kf.x, s[1][0]); s[1][1] = fmaf(a1, kf.y, s[1][1]);
            s[1][2] = fmaf(a1, kf.z, s[1][2]); s[1][3] = fmaf(a1, kf.w, s[1][3]);
            s[2][0] = fmaf(a2, kf.x, s[2][0]); s[2][1] = fmaf(a2, kf.y, s[2][1]);
            s[2][2] = fmaf(a2, kf.z, s[2][2]); s[2][3] = fmaf(a2, kf.w, s[2][3]);
            s[3][0] = fmaf(a3, kf.x, s[3][0]); s[3][1] = fmaf(a3, kf.y, s[3][1]);
            s[3][2] = fmaf(a3, kf.z, s[3][2]); s[3][3] = fmaf(a3, kf.w, s[3][3]);
        }
        // mask
        #pragma unroll
        for (int e = 0; e < 4; ++e) {
            int qpos = q0g + 4 * tm + e;
            #pragma unroll
            for (int f = 0; f < 4; ++f) {
                int kpos = klo + 4 * tn + f;
                int rel = kpos - qpos;
                bool valid = (rel <= 128) & (rel >= -128) & (kpos >= min_key) & (kpos < S_);
                if (!valid) s[e][f] = -1e9f;
            }
        }
        // online softmax across 16 tn lanes
        #pragma unroll
        for (int e = 0; e < 4; ++e) {
            float mx = fmaxf(fmaxf(s[e][0], s[e][1]), fmaxf(s[e][2], s[e][3]));
            #pragma unroll
            for (int st = 1; st < 16; st <<= 1)
                mx = fmaxf(mx, __shfl_xor(mx, st, 64));
            float mn = fmaxf(m[e], mx);
            float sc = __expf(m[e] - mn);
            float ps = 0.f;
            #pragma unroll
            for (int f = 0; f < 4; ++f) { s[e][f] = __expf(s[e][f] - mn); ps += s[e][f]; }
            #pragma unroll
            for (int st = 1; st < 16; st <<= 1)
                ps += __shfl_xor(ps, st, 64);
            lsum[e] = lsum[e] * sc + ps;
            m[e] = mn;
            #pragma unroll
            for (int g = 0; g < 4; ++g) o[e][g] *= sc;
        }
        // P -> LDS, then PV
        #pragma unroll
        for (int e = 0; e < 4; ++e) {
            float4 pv; pv.x = s[e][0]; pv.y = s[e][1]; pv.z = s[e][2]; pv.w = s[e][3];
            *(float4*)&Ps[4 * tm + e][4 * tn] = pv;
        }
        __syncthreads();
        #pragma unroll 8
        for (int j = 0; j < 64; ++j) {
            float a0 = Ps[4 * tm + 0][j], a1 = Ps[4 * tm + 1][j];
            float a2 = Ps[4 * tm + 2][j], a3 = Ps[4 * tm + 3][j];
            float4 vf = *(const float4*)&Vs[j][4 * tn];
            o[0][0] = fmaf(a0, vf.x, o[0][0]); o[0][1] = fmaf(a0, vf.y, o[0][1]);
            o[0][2] = fmaf(a0, vf.z, o[0][2]); o[0][3] = fmaf(a0, vf.w, o[0][3]);
            o[1][0] = fmaf(a1, vf.x, o[1][0]); o[1][1] = fmaf(a1, vf.y, o[1][1]);
            o[1][2] = fmaf(a1, vf.z, o[1][2]); o[1][3] = fmaf(a1, vf.w, o[1][3]);
            o[2][0] = fmaf(a2, vf.x, o[2][0]); o[2][1] = fmaf(a2, vf.y, o[2][1]);
            o[2][2] = fmaf(a2, vf.z, o[2][2]); o[2][3] = fmaf(a2, vf.w, o[2][3]);
            o[3][0] = fmaf(a3, vf.x, o[3][0]); o[3][1] = fmaf(a3, vf.y, o[3][1]);
            o[3][2] = fmaf(a3, vf.z, o[3][2]); o[3][3] = fmaf(a3, vf.w, o[3][3]);
        }
    }
    // epilogue: normalize + bf16 store
    #pragma unroll
    for (int e = 0; e < 4; ++e) {
        float inv = 1.f / lsum[e];
        unsigned int p0 = (unsigned int)f2bf(o[e][0] * inv) | ((unsigned int)f2bf(o[e][1] * inv) << 16);
        unsigned int p1 = (unsigned int)f2bf(o[e][2] * inv) | ((unsigned int)f2bf(o[e][3] * inv) << 16);
        uint2 pk; pk.x = p0; pk.y = p1;
        *(uint2*)(out + ((size_t)b * S_ + q0g + 4 * tm + e) * H_ + h * 64 + 4 * tn) = pk;
    }
}

// ============================================================================
// cls-token query projection (fp32 path): q_cls[b,:] = x[b,0,:] @ Wq_cls + bq
// ============================================================================
__global__ __launch_bounds__(256) void qcls_kernel(
    const float* __restrict__ x, const float* __restrict__ Wqkv,
    const float* __restrict__ bqkv, float* __restrict__ q_cls)
{
    __shared__ float sx[512];
    int idx = blockIdx.x * 256 + threadIdx.x;
    int b = idx >> 9, j = idx & 511;
    for (int i = threadIdx.x; i < 512; i += 256) sx[i] = x[(size_t)b * S_ * H_ + i];
    __syncthreads();
    float s = bqkv[j];
    for (int d = 0; d < 512; ++d) s = fmaf(sx[d], Wqkv[(size_t)d * 1536 + j], s);
    q_cls[idx] = s;
}

// ============================================================================
// cls attention (bf16 k/v): per (b,h) softmax(q.k/8) @ v -> gpre[b,512] fp32
// ============================================================================
__global__ __launch_bounds__(256) void cls_attn_kernel(
    const float* __restrict__ q_cls, const unsigned short* __restrict__ qkv,
    float* __restrict__ gpre)
{
    int b = blockIdx.x >> 3, h = blockIdx.x & 7;
    __shared__ float sQ[64];
    __shared__ float sS[S_];
    __shared__ float red[256];
    __shared__ float part[16][64];
    int t = threadIdx.x;
    if (t < 64) sQ[t] = q_cls[b * H_ + h * 64 + t] * 0.125f;
    __syncthreads();
    const size_t base = (size_t)b * S_ * QKVLD;
    float lmax = -1e30f;
    #pragma unroll 2
    for (int i = 0; i < 16; ++i) {
        int j = t + i * 256;
        const unsigned short* kr = qkv + base + (size_t)j * QKVLD + 512 + h * 64;
        float s = 0.f;
        #pragma unroll
        for (int d8 = 0; d8 < 8; ++d8) {
            uint4 raw = *(const uint4*)(kr + d8 * 8);
            const float* q = &sQ[d8 * 8];
            s = fmaf(q[0], bflo(raw.x), s); s = fmaf(q[1], bfhi(raw.x), s);
            s = fmaf(q[2], bflo(raw.y), s); s = fmaf(q[3], bfhi(raw.y), s);
            s = fmaf(q[4], bflo(raw.z), s); s = fmaf(q[5], bfhi(raw.z), s);
            s = fmaf(q[6], bflo(raw.w), s); s = fmaf(q[7], bfhi(raw.w), s);
        }
        sS[j] = s;
        lmax = fmaxf(lmax, s);
    }
    red[t] = lmax; __syncthreads();
    for (int st = 128; st > 0; st >>= 1) {
        if (t < st) red[t] = fmaxf(red[t], red[t + st]);
        __syncthreads();
    }
    float mx = red[0];
    __syncthreads();
    float ls = 0.f;
    #pragma unroll 2
    for (int i = 0; i < 16; ++i) {
        int j = t + i * 256;
        float p = __expf(sS[j] - mx);
        sS[j] = p;
        ls += p;
    }
    red[t] = ls; __syncthreads();
    for (int st = 128; st > 0; st >>= 1) {
        if (t < st) red[t] += red[t + st];
        __syncthreads();
    }
    float inv = 1.f / red[0];
    int g = t >> 4, d4 = t & 15;
    float4 acc; acc.x = 0.f; acc.y = 0.f; acc.z = 0.f; acc.w = 0.f;
    for (int j = g * 256; j < (g + 1) * 256; ++j) {
        float p = sS[j];
        uint2 raw = *(const uint2*)(qkv + base + (size_t)j * QKVLD + 1024 + h * 64 + d4 * 4);
        acc.x = fmaf(p, bflo(raw.x), acc.x); acc.y = fmaf(p, bfhi(raw.x), acc.y);
        acc.z = fmaf(p, bflo(raw.y), acc.z); acc.w = fmaf(p, bfhi(raw.y), acc.w);
    }
    *(float4*)&part[g][d4 * 4] = acc;
    __syncthreads();
    if (t < 64) {
        float r = 0.f;
        #pragma unroll
        for (int g2 = 0; g2 < 16; ++g2) r += part[g2][t];
        gpre[b * H_ + h * 64 + t] = r * inv;
    }
}

// ============================================================================
// cls Wo projection + LogN scale -> attended row (b,0,:) in bf16
// ============================================================================
__global__ __launch_bounds__(256) void clsproj_kernel(
    const float* __restrict__ gpre, const float* __restrict__ Wo,
    const float* __restrict__ bo, const float* __restrict__ logn,
    unsigned short* __restrict__ attended)
{
    __shared__ float sg[512];
    int idx = blockIdx.x * 256 + threadIdx.x;
    int b = idx >> 9, j = idx & 511;
    for (int i = threadIdx.x; i < 512; i += 256) sg[i] = gpre[b * H_ + i];
    __syncthreads();
    float s = bo[j];
    for (int d = 0; d < 512; ++d) s = fmaf(sg[d], Wo[(size_t)d * H_ + j], s);
    attended[(size_t)b * S_ * H_ + j] = f2bf(s * logn[0]);
}

// ============================================================================
// classifier: out[r,l] = seq[r,:] @ Wc[:,l] + bc[l]  (L=17, seq bf16, out fp32)
// ============================================================================
__global__ __launch_bounds__(256) void logits_kernel(
    const unsigned short* __restrict__ seq, const float* __restrict__ Wc,
    const float* __restrict__ bc, float* __restrict__ out)
{
    __shared__ float sWc[17][516];
    for (int i = threadIdx.x; i < 512 * 17; i += 256) {
        int d = i / 17, lcol = i % 17;
        sWc[lcol][d] = Wc[i];
    }
    __syncthreads();
    int idx = blockIdx.x * 256 + threadIdx.x;
    if (idx >= M_ * 17) return;
    int r = idx / 17, lcol = idx % 17;
    const unsigned short* sr = seq + (size_t)r * H_;
    float s = bc[lcol];
    for (int d8 = 0; d8 < 64; ++d8) {
        uint4 raw = *(const uint4*)(sr + d8 * 8);
        const float* wr = &sWc[lcol][d8 * 8];
        s = fmaf(bflo(raw.x), wr[0], s); s = fmaf(bfhi(raw.x), wr[1], s);
        s = fmaf(bflo(raw.y), wr[2], s); s = fmaf(bfhi(raw.y), wr[3], s);
        s = fmaf(bflo(raw.z), wr[4], s); s = fmaf(bfhi(raw.z), wr[5], s);
        s = fmaf(bflo(raw.w), wr[6], s); s = fmaf(bfhi(raw.w), wr[7], s);
    }
    out[idx] = s;
}

// ============================================================================
extern "C" void kernel_launch(void* const* d_in, const int* in_sizes, int n_in,
                              void* d_out, int out_size, void* d_ws, size_t ws_size,
                              hipStream_t stream) {
    const float* x        = (const float*)d_in[0];
    const float* Wqkv_cls = (const float*)d_in[1];
    const float* bqkv_cls = (const float*)d_in[2];
    const float* Wo_cls   = (const float*)d_in[3];
    const float* bo_cls   = (const float*)d_in[4];
    const float* Wqkv_loc = (const float*)d_in[5];
    const float* bqkv_loc = (const float*)d_in[6];
    const float* Wo_loc   = (const float*)d_in[7];
    const float* bo_loc   = (const float*)d_in[8];
    const float* logn     = (const float*)d_in[9];
    const float* Wqkv_h   = (const float*)d_in[10];
    const float* bqkv_h   = (const float*)d_in[11];
    const float* Wo_h     = (const float*)d_in[12];
    const float* bo_h     = (const float*)d_in[13];
    const float* Wqkv_v   = (const float*)d_in[14];
    const float* bqkv_v   = (const float*)d_in[15];
    const float* Wo_v     = (const float*)d_in[16];
    const float* bo_v     = (const float*)d_in[17];
    const float* W1       = (const float*)d_in[18];
    const float* b1       = (const float*)d_in[19];
    const float* W2       = (const float*)d_in[20];
    const float* b2       = (const float*)d_in[21];
    const float* Wc       = (const float*)d_in[22];
    const float* bc       = (const float*)d_in[23];
    float* out = (float*)d_out;

    // workspace layout in bf16 (unsigned short) elements, ~102 MB total
    unsigned short* wsu = (unsigned short*)d_ws;
    unsigned short* xb        = wsu;                 //  4,194,304 used
    unsigned short* qkv       = wsu +  8388608;      // 12,582,912
    unsigned short* attnout   = wsu + 20971520;      //  4,194,304
    unsigned short* attended  = wsu + 25165824;      //  4,194,304
    unsigned short* combined  = wsu + 29360128;      //  8,388,608
    unsigned short* hidden    = wsu + 37748736;      //  4,194,304
    unsigned short* seq       = wsu + 41943040;      //  4,194,304
    unsigned short* WqkvT_cls = wsu + 46137344;      //    786,432 each
    unsigned short* WqkvT_loc = wsu + 46923776;
    unsigned short* WqkvT_h   = wsu + 47710208;
    unsigned short* WqkvT_v   = wsu + 48496640;
    unsigned short* WoT_loc   = wsu + 49283072;      //    262,144 each
    unsigned short* WoT_h     = wsu + 49545216;
    unsigned short* WoT_v     = wsu + 49807360;
    unsigned short* W2T       = wsu + 50069504;
    unsigned short* W1T       = wsu + 50331648;      //    524,288
    float* q_cls              = (float*)(wsu + 50855936);
    float* gpre               = q_cls + 1024;

    dim3 blk(256);

    // --- conversions ---
    // x has B*S*H = 4,194,304 floats -> n8 = 524288 (FIX: was 2x, OOB crash)
    cvt_kernel<<<dim3(2048), blk, 0, stream>>>(x, xb, 524288);
    wtrans_kernel<<<dim3(48, 16, 4), blk, 0, stream>>>(
        Wqkv_cls, Wqkv_loc, Wqkv_h, Wqkv_v,
        WqkvT_cls, WqkvT_loc, WqkvT_h, WqkvT_v, 512, 1536);
    wtrans_kernel<<<dim3(16, 16, 4), blk, 0, stream>>>(
        Wo_loc, Wo_h, Wo_v, W2, WoT_loc, WoT_h, WoT_v, W2T, 512, 512);
    wtrans_kernel<<<dim3(16, 32, 1), blk, 0, stream>>>(
        W1, W1, W1, W1, W1T, W1T, W1T, W1T, 1024, 512);

    // --- cls path ---
    mgemm_kernel<128, 0><<<dim3(8, 64), blk, 0, stream>>>(
        xb, 512, WqkvT_cls + 512 * 512, 512, bqkv_cls + 512, qkv + 512, 1536, 512);
    qcls_kernel<<<dim3(4), blk, 0, stream>>>(x, Wqkv_cls, bqkv_cls, q_cls);
    cls_attn_kernel<<<dim3(16), blk, 0, stream>>>(q_cls, qkv, gpre);

    // --- loc attention ---
    mgemm_kernel<128, 0><<<dim3(12, 64), blk, 0, stream>>>(
        xb, 512, WqkvT_loc, 512, bqkv_loc, qkv, 1536, 512);
    wattn_kernel<<<dim3(64, 8, 2), blk, 0, stream>>>(qkv, attnout, 1);
    mgemm_kernel<64, 0><<<dim3(4, 128), blk, 0, stream>>>(
        attnout, 512, WoT_loc, 512, bo_loc, attended, 512, 512);
    clsproj_kernel<<<dim3(4), blk, 0, stream>>>(gpre, Wo_cls, bo_cls, logn, attended);

    // --- h attention ---
    mgemm_kernel<128, 0><<<dim3(12, 64), blk, 0, stream>>>(
        attended, 512, WqkvT_h, 512, bqkv_h, qkv, 1536, 512);
    wattn_kernel<<<dim3(64, 8, 2), blk, 0, stream>>>(qkv, attnout, 0);
    mgemm_kernel<64, 0><<<dim3(4, 128), blk, 0, stream>>>(
        attnout, 512, WoT_h, 512, bo_h, combined, 1024, 512);

    // --- v attention ---
    mgemm_kernel<128, 0><<<dim3(12, 64), blk, 0, stream>>>(
        attended, 512, WqkvT_v, 512, bqkv_v, qkv, 1536, 512);
    wattn_kernel<<<dim3(64, 8, 2), blk, 0, stream>>>(qkv, attnout, 0);
    mgemm_kernel<64, 0><<<dim3(4, 128), blk, 0, stream>>>(
        attnout, 512, WoT_v, 512, bo_v, combined + 512, 1024, 512);

    // --- MLP + classifier ---
    mgemm_kernel<64, 1><<<dim3(4, 128), blk, 0, stream>>>(
        combined, 1024, W1T, 1024, b1, hidden, 512, 1024);
    mgemm_kernel<64, 0><<<dim3(4, 128), blk, 0, stream>>>(
        hidden, 512, W2T, 512, b2, seq, 512, 512);
    logits_kernel<<<dim3((M_ * 17 + 255) / 256), blk, 0, stream>>>(seq, Wc, bc, out);
}

// Round 7
// 440.880 us; speedup vs baseline: 3.6091x; 1.7767x over previous
//
#include <hip/hip_runtime.h>

#define S_ 4096
#define H_ 512
#define QKVLD 1536
#define M_ 8192

typedef __attribute__((ext_vector_type(8))) short s16x8;   // 8 bf16 = 4 VGPR
typedef __attribute__((ext_vector_type(4))) float f32x4;   // MFMA acc frag

__device__ __forceinline__ float bflo(unsigned int w) { return __uint_as_float(w << 16); }
__device__ __forceinline__ float bfhi(unsigned int w) { return __uint_as_float(w & 0xFFFF0000u); }
__device__ __forceinline__ float bf2f(unsigned short u) { return __uint_as_float(((unsigned int)u) << 16); }
__device__ __forceinline__ unsigned short f2bf(float f) {   // RNE
    unsigned int x = __float_as_uint(f);
    return (unsigned short)((x + 0x7FFFu + ((x >> 16) & 1u)) >> 16);
}
__device__ __forceinline__ void gload_lds16(const void* g, void* l) {
    __builtin_amdgcn_global_load_lds(
        (const __attribute__((address_space(1))) unsigned int*)g,
        (__attribute__((address_space(3))) unsigned int*)l, 16, 0, 0);
}

// ============================================================================
// fp32 -> bf16 cast (x input), 8 elts/thread.  n8 = total_elements / 8.
// ============================================================================
__global__ __launch_bounds__(256) void cvt_kernel(
    const float* __restrict__ in, unsigned short* __restrict__ out, int n8)
{
    int i = blockIdx.x * 256 + threadIdx.x;
    if (i >= n8) return;
    float4 a = *(const float4*)(in + (size_t)i * 8);
    float4 b = *(const float4*)(in + (size_t)i * 8 + 4);
    uint4 pk;
    pk.x = (unsigned int)f2bf(a.x) | ((unsigned int)f2bf(a.y) << 16);
    pk.y = (unsigned int)f2bf(a.z) | ((unsigned int)f2bf(a.w) << 16);
    pk.z = (unsigned int)f2bf(b.x) | ((unsigned int)f2bf(b.y) << 16);
    pk.w = (unsigned int)f2bf(b.z) | ((unsigned int)f2bf(b.w) << 16);
    *(uint4*)(out + (size_t)i * 8) = pk;
}

// ============================================================================
// Weight transpose + cast: in fp32 [K][N] -> out bf16 [N][K]; 4 matrices via z.
// ============================================================================
__global__ __launch_bounds__(256) void wtrans_kernel(
    const float* __restrict__ p0, const float* __restrict__ p1,
    const float* __restrict__ p2, const float* __restrict__ p3,
    unsigned short* o0, unsigned short* o1,
    unsigned short* o2, unsigned short* o3,
    int K, int N)
{
    const float* in; unsigned short* out;
    switch (blockIdx.z) {
        case 0:  in = p0; out = o0; break;
        case 1:  in = p1; out = o1; break;
        case 2:  in = p2; out = o2; break;
        default: in = p3; out = o3; break;
    }
    __shared__ float tile[32][33];
    int n0 = blockIdx.x * 32, k0 = blockIdx.y * 32;
    int tx = threadIdx.x & 31, ty = threadIdx.x >> 5;   // 32 x 8
    #pragma unroll
    for (int i = 0; i < 4; ++i) {
        int k = k0 + ty * 4 + i;
        tile[ty * 4 + i][tx] = in[(size_t)k * N + n0 + tx];
    }
    __syncthreads();
    #pragma unroll
    for (int i = 0; i < 4; ++i) {
        int n = n0 + ty * 4 + i;
        out[(size_t)n * K + k0 + tx] = f2bf(tile[tx][ty * 4 + i]);
    }
}

// ============================================================================
// bf16 MFMA GEMM (unchanged from Round 6, hardware-verified).
// ============================================================================
template<int BM, int RELU>
__global__ __launch_bounds__(256) void mgemm_kernel(
    const unsigned short* __restrict__ A, int lda,
    const unsigned short* __restrict__ Bt, int ldb,
    const float* __restrict__ bias,
    unsigned short* __restrict__ C, int ldc, int K)
{
    constexpr int MF = BM / 32;
    constexpr int ASEG = BM / 32;
    __shared__ __align__(16) unsigned short As[BM * 64];
    __shared__ __align__(16) unsigned short Bs[128 * 64];
    const int t = threadIdx.x;
    const int w = t >> 6, l = t & 63;
    const int wr = w >> 1, wc = w & 1;
    const int row0 = blockIdx.y * BM, col0 = blockIdx.x * 128;
    const int lr = l >> 3;
    const int lc = l & 7;

    f32x4 acc[MF][4];
    #pragma unroll
    for (int i = 0; i < MF; ++i)
        #pragma unroll
        for (int j = 0; j < 4; ++j) acc[i][j] = {0.f, 0.f, 0.f, 0.f};

    for (int k0 = 0; k0 < K; k0 += 64) {
        __syncthreads();
        #pragma unroll
        for (int i = 0; i < ASEG; ++i) {
            int seg = w * ASEG + i;
            int r = seg * 8 + lr;
            int kc = lc ^ (r & 7);
            gload_lds16(A + (size_t)(row0 + r) * lda + k0 + kc * 8,
                        (void*)(As + seg * 512));
        }
        #pragma unroll
        for (int i = 0; i < 4; ++i) {
            int seg = w * 4 + i;
            int r = seg * 8 + lr;
            int kc = lc ^ (r & 7);
            gload_lds16(Bt + (size_t)(col0 + r) * ldb + k0 + kc * 8,
                        (void*)(Bs + seg * 512));
        }
        __syncthreads();

        s16x8 af[MF][2], bf[4][2];
        #pragma unroll
        for (int mf = 0; mf < MF; ++mf)
            #pragma unroll
            for (int kk = 0; kk < 2; ++kk) {
                int r = wr * (BM / 2) + mf * 16 + (l & 15);
                int ch = (kk * 4 + (l >> 4)) ^ (r & 7);
                af[mf][kk] = *(const s16x8*)(As + r * 64 + ch * 8);
            }
        #pragma unroll
        for (int nf = 0; nf < 4; ++nf)
            #pragma unroll
            for (int kk = 0; kk < 2; ++kk) {
                int r = wc * 64 + nf * 16 + (l & 15);
                int ch = (kk * 4 + (l >> 4)) ^ (r & 7);
                bf[nf][kk] = *(const s16x8*)(Bs + r * 64 + ch * 8);
            }
        #pragma unroll
        for (int kk = 0; kk < 2; ++kk)
            #pragma unroll
            for (int mf = 0; mf < MF; ++mf)
                #pragma unroll
                for (int nf = 0; nf < 4; ++nf)
                    acc[mf][nf] = __builtin_amdgcn_mfma_f32_16x16x32_bf16(
                        af[mf][kk], bf[nf][kk], acc[mf][nf], 0, 0, 0);
    }

    #pragma unroll
    for (int mf = 0; mf < MF; ++mf)
        #pragma unroll
        for (int nf = 0; nf < 4; ++nf) {
            int col = col0 + wc * 64 + nf * 16 + (l & 15);
            float bb = bias[col];
            #pragma unroll
            for (int r4 = 0; r4 < 4; ++r4) {
                int row = row0 + wr * (BM / 2) + mf * 16 + (l >> 4) * 4 + r4;
                float v = acc[mf][nf][r4] + bb;
                if (RELU) v = fmaxf(v, 0.f);
                C[(size_t)row * ldc + col] = f2bf(v);
            }
        }
}

// ============================================================================
// Windowed (banded) MHA, flash-style, MFMA version.
// Block = (64-query tile n, head h, batch b), 256 threads = 4 waves.
// Wave w owns q rows [w*16, w*16+16). 5 K-chunks of 64; every non-skipped
// chunk is fully in [0,S) (chunks 64-aligned, S%64==0), so staging never
// needs bounds masking — only the positional band mask on scores.
// QK^T: A=Q frags (global, hoisted), B=K natural [kpos][d] (gload_lds +
// mgemm's verified XOR swizzle). Softmax fp32 in C-frag regs (16-lane
// shfl_xor row reduce). P->bf16->Ps (wave-local rows, no barrier needed).
// PV: A=Ps frags, B=V transposed [d][kpos] (reg-transpose staging, stride
// 72 = 16B-aligned rows, <=2-way banks).
// ============================================================================
__global__ __launch_bounds__(256) void wattn_kernel(
    const unsigned short* __restrict__ qkv,
    unsigned short* __restrict__ out,      // [B,S,512] bf16
    int min_key)
{
    const int n = blockIdx.x, h = blockIdx.y, b = blockIdx.z;
    const int t = threadIdx.x;
    const int w = t >> 6, l = t & 63;
    const int l4 = l >> 4, lm = l & 15;

    __shared__ __align__(16) unsigned short Ks[64 * 64];   //  8 KB
    __shared__ __align__(16) unsigned short Vt[64 * 72];   //  9 KB  [d][kpos]
    __shared__ __align__(16) unsigned short Ps[64 * 72];   //  9 KB  [q][kpos]

    const int q0g = n * 64;
    const size_t base = (size_t)b * S_ * QKVLD;

    // Q A-frags, hoisted: row q = q0g + w*16 + lm, elems d = l4*8 + kk*32
    s16x8 qf[2];
    {
        const unsigned short* qrow =
            qkv + base + (size_t)(q0g + w * 16 + lm) * QKVLD + h * 64 + l4 * 8;
        qf[0] = *(const s16x8*)(qrow);
        qf[1] = *(const s16x8*)(qrow + 32);
    }

    float m[4], lsum[4];
    f32x4 oacc[4];
    #pragma unroll
    for (int e = 0; e < 4; ++e) {
        m[e] = -1e30f; lsum[e] = 0.f;
        oacc[e] = {0.f, 0.f, 0.f, 0.f};
    }

    const int lr = l >> 3, lc = l & 7;   // K-staging coords

    for (int c = 0; c < 5; ++c) {
        const int klo = q0g - 128 + c * 64;
        if (klo < 0 || klo >= S_) continue;   // uniform; chunk else fully valid
        __syncthreads();   // prev chunk's LDS readers done

        // --- stage K [kpos][d] via global_load_lds, pre-swizzled source
        #pragma unroll
        for (int i = 0; i < 2; ++i) {
            int seg = w * 2 + i;
            int r = seg * 8 + lr;
            int kc = lc ^ (r & 7);
            gload_lds16(qkv + base + (size_t)(klo + r) * QKVLD + 512 + h * 64 + kc * 8,
                        (void*)(Ks + seg * 512));
        }
        // --- stage V transposed [d][kpos]: coalesced row loads, packed writes
        {
            int jp = (t & 31) * 2, ds = (t >> 5) * 8;
            uint4 r0 = *(const uint4*)(qkv + base + (size_t)(klo + jp) * QKVLD + 1024 + h * 64 + ds);
            uint4 r1 = *(const uint4*)(qkv + base + (size_t)(klo + jp + 1) * QKVLD + 1024 + h * 64 + ds);
            const unsigned short* va = (const unsigned short*)&r0;
            const unsigned short* vb = (const unsigned short*)&r1;
            #pragma unroll
            for (int j = 0; j < 8; ++j)
                *(unsigned int*)(Vt + (ds + j) * 72 + jp) =
                    (unsigned int)va[j] | ((unsigned int)vb[j] << 16);
        }
        __syncthreads();

        // --- QK^T: 16q x 64k per wave
        f32x4 sf[4];
        #pragma unroll
        for (int nf = 0; nf < 4; ++nf) sf[nf] = {0.f, 0.f, 0.f, 0.f};
        #pragma unroll
        for (int kk = 0; kk < 2; ++kk)
            #pragma unroll
            for (int nf = 0; nf < 4; ++nf) {
                int r = nf * 16 + lm;
                int ch = (kk * 4 + l4) ^ (r & 7);
                s16x8 kf = *(const s16x8*)(Ks + r * 64 + ch * 8);
                sf[nf] = __builtin_amdgcn_mfma_f32_16x16x32_bf16(qf[kk], kf, sf[nf], 0, 0, 0);
            }

        // --- scale + band mask + online softmax (row = 16-lane group)
        #pragma unroll
        for (int r4 = 0; r4 < 4; ++r4) {
            const int qpos = q0g + w * 16 + l4 * 4 + r4;
            float sv[4];
            #pragma unroll
            for (int nf = 0; nf < 4; ++nf) {
                int kpos = klo + nf * 16 + lm;
                int rel = kpos - qpos;
                bool valid = (rel <= 128) & (rel >= -128) & (kpos >= min_key);
                sv[nf] = valid ? sf[nf][r4] * 0.125f : -1e9f;
            }
            float mx = fmaxf(fmaxf(sv[0], sv[1]), fmaxf(sv[2], sv[3]));
            #pragma unroll
            for (int st = 1; st < 16; st <<= 1)
                mx = fmaxf(mx, __shfl_xor(mx, st, 64));
            float mn = fmaxf(m[r4], mx);
            float sc = __expf(m[r4] - mn);
            float ps = 0.f;
            #pragma unroll
            for (int nf = 0; nf < 4; ++nf) {
                sv[nf] = __expf(sv[nf] - mn);
                ps += sv[nf];
            }
            #pragma unroll
            for (int st = 1; st < 16; st <<= 1)
                ps += __shfl_xor(ps, st, 64);
            lsum[r4] = lsum[r4] * sc + ps;
            m[r4] = mn;
            #pragma unroll
            for (int nf = 0; nf < 4; ++nf) oacc[nf][r4] *= sc;
            // P -> bf16 -> Ps (wave-local q rows; compiler orders LDS RAW)
            const int prow = w * 16 + l4 * 4 + r4;
            #pragma unroll
            for (int nf = 0; nf < 4; ++nf)
                Ps[prow * 72 + nf * 16 + lm] = f2bf(sv[nf]);
        }

        // --- PV: O[16q][64d] += P[16q][64k] @ V[64k][64d]
        #pragma unroll
        for (int kk = 0; kk < 2; ++kk) {
            s16x8 pf = *(const s16x8*)(Ps + (w * 16 + lm) * 72 + l4 * 8 + kk * 32);
            #pragma unroll
            for (int nf = 0; nf < 4; ++nf) {
                s16x8 vf = *(const s16x8*)(Vt + (nf * 16 + lm) * 72 + l4 * 8 + kk * 32);
                oacc[nf] = __builtin_amdgcn_mfma_f32_16x16x32_bf16(pf, vf, oacc[nf], 0, 0, 0);
            }
        }
    }

    // epilogue: normalize + bf16 store
    #pragma unroll
    for (int r4 = 0; r4 < 4; ++r4) {
        float inv = 1.f / lsum[r4];
        size_t row = (size_t)b * S_ + q0g + w * 16 + l4 * 4 + r4;
        #pragma unroll
        for (int nf = 0; nf < 4; ++nf)
            out[row * H_ + h * 64 + nf * 16 + lm] = f2bf(oacc[nf][r4] * inv);
    }
}

// ============================================================================
// cls-token query projection (fp32 path): q_cls[b,:] = x[b,0,:] @ Wq_cls + bq
// ============================================================================
__global__ __launch_bounds__(256) void qcls_kernel(
    const float* __restrict__ x, const float* __restrict__ Wqkv,
    const float* __restrict__ bqkv, float* __restrict__ q_cls)
{
    __shared__ float sx[512];
    int idx = blockIdx.x * 256 + threadIdx.x;
    int b = idx >> 9, j = idx & 511;
    for (int i = threadIdx.x; i < 512; i += 256) sx[i] = x[(size_t)b * S_ * H_ + i];
    __syncthreads();
    float s = bqkv[j];
    for (int d = 0; d < 512; ++d) s = fmaf(sx[d], Wqkv[(size_t)d * 1536 + j], s);
    q_cls[idx] = s;
}

// ============================================================================
// cls attention (bf16 k/v): per (b,h) softmax(q.k/8) @ v -> gpre[b,512] fp32
// ============================================================================
__global__ __launch_bounds__(256) void cls_attn_kernel(
    const float* __restrict__ q_cls, const unsigned short* __restrict__ qkv,
    float* __restrict__ gpre)
{
    int b = blockIdx.x >> 3, h = blockIdx.x & 7;
    __shared__ float sQ[64];
    __shared__ float sS[S_];
    __shared__ float red[256];
    __shared__ float part[16][64];
    int t = threadIdx.x;
    if (t < 64) sQ[t] = q_cls[b * H_ + h * 64 + t] * 0.125f;
    __syncthreads();
    const size_t base = (size_t)b * S_ * QKVLD;
    float lmax = -1e30f;
    #pragma unroll 2
    for (int i = 0; i < 16; ++i) {
        int j = t + i * 256;
        const unsigned short* kr = qkv + base + (size_t)j * QKVLD + 512 + h * 64;
        float s = 0.f;
        #pragma unroll
        for (int d8 = 0; d8 < 8; ++d8) {
            uint4 raw = *(const uint4*)(kr + d8 * 8);
            const float* q = &sQ[d8 * 8];
            s = fmaf(q[0], bflo(raw.x), s); s = fmaf(q[1], bfhi(raw.x), s);
            s = fmaf(q[2], bflo(raw.y), s); s = fmaf(q[3], bfhi(raw.y), s);
            s = fmaf(q[4], bflo(raw.z), s); s = fmaf(q[5], bfhi(raw.z), s);
            s = fmaf(q[6], bflo(raw.w), s); s = fmaf(q[7], bfhi(raw.w), s);
        }
        sS[j] = s;
        lmax = fmaxf(lmax, s);
    }
    red[t] = lmax; __syncthreads();
    for (int st = 128; st > 0; st >>= 1) {
        if (t < st) red[t] = fmaxf(red[t], red[t + st]);
        __syncthreads();
    }
    float mx = red[0];
    __syncthreads();
    float ls = 0.f;
    #pragma unroll 2
    for (int i = 0; i < 16; ++i) {
        int j = t + i * 256;
        float p = __expf(sS[j] - mx);
        sS[j] = p;
        ls += p;
    }
    red[t] = ls; __syncthreads();
    for (int st = 128; st > 0; st >>= 1) {
        if (t < st) red[t] += red[t + st];
        __syncthreads();
    }
    float inv = 1.f / red[0];
    int g = t >> 4, d4 = t & 15;
    float4 acc; acc.x = 0.f; acc.y = 0.f; acc.z = 0.f; acc.w = 0.f;
    for (int j = g * 256; j < (g + 1) * 256; ++j) {
        float p = sS[j];
        uint2 raw = *(const uint2*)(qkv + base + (size_t)j * QKVLD + 1024 + h * 64 + d4 * 4);
        acc.x = fmaf(p, bflo(raw.x), acc.x); acc.y = fmaf(p, bfhi(raw.x), acc.y);
        acc.z = fmaf(p, bflo(raw.y), acc.z); acc.w = fmaf(p, bfhi(raw.y), acc.w);
    }
    *(float4*)&part[g][d4 * 4] = acc;
    __syncthreads();
    if (t < 64) {
        float r = 0.f;
        #pragma unroll
        for (int g2 = 0; g2 < 16; ++g2) r += part[g2][t];
        gpre[b * H_ + h * 64 + t] = r * inv;
    }
}

// ============================================================================
// cls Wo projection + LogN scale -> attended row (b,0,:) in bf16
// ============================================================================
__global__ __launch_bounds__(256) void clsproj_kernel(
    const float* __restrict__ gpre, const float* __restrict__ Wo,
    const float* __restrict__ bo, const float* __restrict__ logn,
    unsigned short* __restrict__ attended)
{
    __shared__ float sg[512];
    int idx = blockIdx.x * 256 + threadIdx.x;
    int b = idx >> 9, j = idx & 511;
    for (int i = threadIdx.x; i < 512; i += 256) sg[i] = gpre[b * H_ + i];
    __syncthreads();
    float s = bo[j];
    for (int d = 0; d < 512; ++d) s = fmaf(sg[d], Wo[(size_t)d * H_ + j], s);
    attended[(size_t)b * S_ * H_ + j] = f2bf(s * logn[0]);
}

// ============================================================================
// classifier: out[r,l] = seq[r,:] @ Wc[:,l] + bc[l]  (L=17, seq bf16, out fp32)
// ============================================================================
__global__ __launch_bounds__(256) void logits_kernel(
    const unsigned short* __restrict__ seq, const float* __restrict__ Wc,
    const float* __restrict__ bc, float* __restrict__ out)
{
    __shared__ float sWc[17][516];
    for (int i = threadIdx.x; i < 512 * 17; i += 256) {
        int d = i / 17, lcol = i % 17;
        sWc[lcol][d] = Wc[i];
    }
    __syncthreads();
    int idx = blockIdx.x * 256 + threadIdx.x;
    if (idx >= M_ * 17) return;
    int r = idx / 17, lcol = idx % 17;
    const unsigned short* sr = seq + (size_t)r * H_;
    float s = bc[lcol];
    for (int d8 = 0; d8 < 64; ++d8) {
        uint4 raw = *(const uint4*)(sr + d8 * 8);
        const float* wr = &sWc[lcol][d8 * 8];
        s = fmaf(bflo(raw.x), wr[0], s); s = fmaf(bfhi(raw.x), wr[1], s);
        s = fmaf(bflo(raw.y), wr[2], s); s = fmaf(bfhi(raw.y), wr[3], s);
        s = fmaf(bflo(raw.z), wr[4], s); s = fmaf(bfhi(raw.z), wr[5], s);
        s = fmaf(bflo(raw.w), wr[6], s); s = fmaf(bfhi(raw.w), wr[7], s);
    }
    out[idx] = s;
}

// ============================================================================
extern "C" void kernel_launch(void* const* d_in, const int* in_sizes, int n_in,
                              void* d_out, int out_size, void* d_ws, size_t ws_size,
                              hipStream_t stream) {
    const float* x        = (const float*)d_in[0];
    const float* Wqkv_cls = (const float*)d_in[1];
    const float* bqkv_cls = (const float*)d_in[2];
    const float* Wo_cls   = (const float*)d_in[3];
    const float* bo_cls   = (const float*)d_in[4];
    const float* Wqkv_loc = (const float*)d_in[5];
    const float* bqkv_loc = (const float*)d_in[6];
    const float* Wo_loc   = (const float*)d_in[7];
    const float* bo_loc   = (const float*)d_in[8];
    const float* logn     = (const float*)d_in[9];
    const float* Wqkv_h   = (const float*)d_in[10];
    const float* bqkv_h   = (const float*)d_in[11];
    const float* Wo_h     = (const float*)d_in[12];
    const float* bo_h     = (const float*)d_in[13];
    const float* Wqkv_v   = (const float*)d_in[14];
    const float* bqkv_v   = (const float*)d_in[15];
    const float* Wo_v     = (const float*)d_in[16];
    const float* bo_v     = (const float*)d_in[17];
    const float* W1       = (const float*)d_in[18];
    const float* b1       = (const float*)d_in[19];
    const float* W2       = (const float*)d_in[20];
    const float* b2       = (const float*)d_in[21];
    const float* Wc       = (const float*)d_in[22];
    const float* bc       = (const float*)d_in[23];
    float* out = (float*)d_out;

    // workspace layout in bf16 (unsigned short) elements, ~102 MB total
    unsigned short* wsu = (unsigned short*)d_ws;
    unsigned short* xb        = wsu;                 //  4,194,304 used
    unsigned short* qkv       = wsu +  8388608;      // 12,582,912
    unsigned short* attnout   = wsu + 20971520;      //  4,194,304
    unsigned short* attended  = wsu + 25165824;      //  4,194,304
    unsigned short* combined  = wsu + 29360128;      //  8,388,608
    unsigned short* hidden    = wsu + 37748736;      //  4,194,304
    unsigned short* seq       = wsu + 41943040;      //  4,194,304
    unsigned short* WqkvT_cls = wsu + 46137344;      //    786,432 each
    unsigned short* WqkvT_loc = wsu + 46923776;
    unsigned short* WqkvT_h   = wsu + 47710208;
    unsigned short* WqkvT_v   = wsu + 48496640;
    unsigned short* WoT_loc   = wsu + 49283072;      //    262,144 each
    unsigned short* WoT_h     = wsu + 49545216;
    unsigned short* WoT_v     = wsu + 49807360;
    unsigned short* W2T       = wsu + 50069504;
    unsigned short* W1T       = wsu + 50331648;      //    524,288
    float* q_cls              = (float*)(wsu + 50855936);
    float* gpre               = q_cls + 1024;

    dim3 blk(256);

    // --- conversions ---
    cvt_kernel<<<dim3(2048), blk, 0, stream>>>(x, xb, 524288);
    wtrans_kernel<<<dim3(48, 16, 4), blk, 0, stream>>>(
        Wqkv_cls, Wqkv_loc, Wqkv_h, Wqkv_v,
        WqkvT_cls, WqkvT_loc, WqkvT_h, WqkvT_v, 512, 1536);
    wtrans_kernel<<<dim3(16, 16, 4), blk, 0, stream>>>(
        Wo_loc, Wo_h, Wo_v, W2, WoT_loc, WoT_h, WoT_v, W2T, 512, 512);
    wtrans_kernel<<<dim3(16, 32, 1), blk, 0, stream>>>(
        W1, W1, W1, W1, W1T, W1T, W1T, W1T, 1024, 512);

    // --- cls path ---
    mgemm_kernel<128, 0><<<dim3(8, 64), blk, 0, stream>>>(
        xb, 512, WqkvT_cls + 512 * 512, 512, bqkv_cls + 512, qkv + 512, 1536, 512);
    qcls_kernel<<<dim3(4), blk, 0, stream>>>(x, Wqkv_cls, bqkv_cls, q_cls);
    cls_attn_kernel<<<dim3(16), blk, 0, stream>>>(q_cls, qkv, gpre);

    // --- loc attention ---
    mgemm_kernel<128, 0><<<dim3(12, 64), blk, 0, stream>>>(
        xb, 512, WqkvT_loc, 512, bqkv_loc, qkv, 1536, 512);
    wattn_kernel<<<dim3(64, 8, 2), blk, 0, stream>>>(qkv, attnout, 1);
    mgemm_kernel<64, 0><<<dim3(4, 128), blk, 0, stream>>>(
        attnout, 512, WoT_loc, 512, bo_loc, attended, 512, 512);
    clsproj_kernel<<<dim3(4), blk, 0, stream>>>(gpre, Wo_cls, bo_cls, logn, attended);

    // --- h attention ---
    mgemm_kernel<128, 0><<<dim3(12, 64), blk, 0, stream>>>(
        attended, 512, WqkvT_h, 512, bqkv_h, qkv, 1536, 512);
    wattn_kernel<<<dim3(64, 8, 2), blk, 0, stream>>>(qkv, attnout, 0);
    mgemm_kernel<64, 0><<<dim3(4, 128), blk, 0, stream>>>(
        attnout, 512, WoT_h, 512, bo_h, combined, 1024, 512);

    // --- v attention ---
    mgemm_kernel<128, 0><<<dim3(12, 64), blk, 0, stream>>>(
        attended, 512, WqkvT_v, 512, bqkv_v, qkv, 1536, 512);
    wattn_kernel<<<dim3(64, 8, 2), blk, 0, stream>>>(qkv, attnout, 0);
    mgemm_kernel<64, 0><<<dim3(4, 128), blk, 0, stream>>>(
        attnout, 512, WoT_v, 512, bo_v, combined + 512, 1024, 512);

    // --- MLP + classifier ---
    mgemm_kernel<64, 1><<<dim3(4, 128), blk, 0, stream>>>(
        combined, 1024, W1T, 1024, b1, hidden, 512, 1024);
    mgemm_kernel<64, 0><<<dim3(4, 128), blk, 0, stream>>>(
        hidden, 512, W2T, 512, b2, seq, 512, 512);
    logits_kernel<<<dim3((M_ * 17 + 255) / 256), blk, 0, stream>>>(seq, Wc, bc, out);
}

// Round 9
// 358.362 us; speedup vs baseline: 4.4401x; 1.2303x over previous
//
#include <hip/hip_runtime.h>

#define S_ 4096
#define H_ 512
#define QKVLD 1536
#define M_ 8192
#define CCH 8   // cls-attention key chunks (512 keys each)

typedef __attribute__((ext_vector_type(8))) short s16x8;   // 8 bf16 = 4 VGPR
typedef __attribute__((ext_vector_type(4))) float f32x4;   // MFMA acc frag

__device__ __forceinline__ float bflo(unsigned int w) { return __uint_as_float(w << 16); }
__device__ __forceinline__ float bfhi(unsigned int w) { return __uint_as_float(w & 0xFFFF0000u); }
__device__ __forceinline__ float bf2f(unsigned short u) { return __uint_as_float(((unsigned int)u) << 16); }
__device__ __forceinline__ unsigned short f2bf(float f) {   // RNE
    unsigned int x = __float_as_uint(f);
    return (unsigned short)((x + 0x7FFFu + ((x >> 16) & 1u)) >> 16);
}
__device__ __forceinline__ void gload_lds16(const void* g, void* l) {
    __builtin_amdgcn_global_load_lds(
        (const __attribute__((address_space(1))) unsigned int*)g,
        (__attribute__((address_space(3))) unsigned int*)l, 16, 0, 0);
}

// ============================================================================
// fp32 -> bf16 cast (x input), 8 elts/thread.  n8 = total_elements / 8.
// ============================================================================
__global__ __launch_bounds__(256) void cvt_kernel(
    const float* __restrict__ in, unsigned short* __restrict__ out, int n8)
{
    int i = blockIdx.x * 256 + threadIdx.x;
    if (i >= n8) return;
    float4 a = *(const float4*)(in + (size_t)i * 8);
    float4 b = *(const float4*)(in + (size_t)i * 8 + 4);
    uint4 pk;
    pk.x = (unsigned int)f2bf(a.x) | ((unsigned int)f2bf(a.y) << 16);
    pk.y = (unsigned int)f2bf(a.z) | ((unsigned int)f2bf(a.w) << 16);
    pk.z = (unsigned int)f2bf(b.x) | ((unsigned int)f2bf(b.y) << 16);
    pk.w = (unsigned int)f2bf(b.z) | ((unsigned int)f2bf(b.w) << 16);
    *(uint4*)(out + (size_t)i * 8) = pk;
}

// ============================================================================
// Weight transpose + cast: in fp32 [K][N] -> out bf16 [N][K]; 4 matrices via z.
// ============================================================================
__global__ __launch_bounds__(256) void wtrans_kernel(
    const float* __restrict__ p0, const float* __restrict__ p1,
    const float* __restrict__ p2, const float* __restrict__ p3,
    unsigned short* o0, unsigned short* o1,
    unsigned short* o2, unsigned short* o3,
    int K, int N)
{
    const float* in; unsigned short* out;
    switch (blockIdx.z) {
        case 0:  in = p0; out = o0; break;
        case 1:  in = p1; out = o1; break;
        case 2:  in = p2; out = o2; break;
        default: in = p3; out = o3; break;
    }
    __shared__ float tile[32][33];
    int n0 = blockIdx.x * 32, k0 = blockIdx.y * 32;
    int tx = threadIdx.x & 31, ty = threadIdx.x >> 5;   // 32 x 8
    #pragma unroll
    for (int i = 0; i < 4; ++i) {
        int k = k0 + ty * 4 + i;
        tile[ty * 4 + i][tx] = in[(size_t)k * N + n0 + tx];
    }
    __syncthreads();
    #pragma unroll
    for (int i = 0; i < 4; ++i) {
        int n = n0 + ty * 4 + i;
        out[(size_t)n * K + k0 + tx] = f2bf(tile[tx][ty * 4 + i]);
    }
}

// ============================================================================
// bf16 MFMA GEMM (hardware-verified, unchanged).
// ============================================================================
template<int BM, int RELU>
__global__ __launch_bounds__(256) void mgemm_kernel(
    const unsigned short* __restrict__ A, int lda,
    const unsigned short* __restrict__ Bt, int ldb,
    const float* __restrict__ bias,
    unsigned short* __restrict__ C, int ldc, int K)
{
    constexpr int MF = BM / 32;
    constexpr int ASEG = BM / 32;
    __shared__ __align__(16) unsigned short As[BM * 64];
    __shared__ __align__(16) unsigned short Bs[128 * 64];
    const int t = threadIdx.x;
    const int w = t >> 6, l = t & 63;
    const int wr = w >> 1, wc = w & 1;
    const int row0 = blockIdx.y * BM, col0 = blockIdx.x * 128;
    const int lr = l >> 3;
    const int lc = l & 7;

    f32x4 acc[MF][4];
    #pragma unroll
    for (int i = 0; i < MF; ++i)
        #pragma unroll
        for (int j = 0; j < 4; ++j) acc[i][j] = {0.f, 0.f, 0.f, 0.f};

    for (int k0 = 0; k0 < K; k0 += 64) {
        __syncthreads();
        #pragma unroll
        for (int i = 0; i < ASEG; ++i) {
            int seg = w * ASEG + i;
            int r = seg * 8 + lr;
            int kc = lc ^ (r & 7);
            gload_lds16(A + (size_t)(row0 + r) * lda + k0 + kc * 8,
                        (void*)(As + seg * 512));
        }
        #pragma unroll
        for (int i = 0; i < 4; ++i) {
            int seg = w * 4 + i;
            int r = seg * 8 + lr;
            int kc = lc ^ (r & 7);
            gload_lds16(Bt + (size_t)(col0 + r) * ldb + k0 + kc * 8,
                        (void*)(Bs + seg * 512));
        }
        __syncthreads();

        s16x8 af[MF][2], bf[4][2];
        #pragma unroll
        for (int mf = 0; mf < MF; ++mf)
            #pragma unroll
            for (int kk = 0; kk < 2; ++kk) {
                int r = wr * (BM / 2) + mf * 16 + (l & 15);
                int ch = (kk * 4 + (l >> 4)) ^ (r & 7);
                af[mf][kk] = *(const s16x8*)(As + r * 64 + ch * 8);
            }
        #pragma unroll
        for (int nf = 0; nf < 4; ++nf)
            #pragma unroll
            for (int kk = 0; kk < 2; ++kk) {
                int r = wc * 64 + nf * 16 + (l & 15);
                int ch = (kk * 4 + (l >> 4)) ^ (r & 7);
                bf[nf][kk] = *(const s16x8*)(Bs + r * 64 + ch * 8);
            }
        #pragma unroll
        for (int kk = 0; kk < 2; ++kk)
            #pragma unroll
            for (int mf = 0; mf < MF; ++mf)
                #pragma unroll
                for (int nf = 0; nf < 4; ++nf)
                    acc[mf][nf] = __builtin_amdgcn_mfma_f32_16x16x32_bf16(
                        af[mf][kk], bf[nf][kk], acc[mf][nf], 0, 0, 0);
    }

    #pragma unroll
    for (int mf = 0; mf < MF; ++mf)
        #pragma unroll
        for (int nf = 0; nf < 4; ++nf) {
            int col = col0 + wc * 64 + nf * 16 + (l & 15);
            float bb = bias[col];
            #pragma unroll
            for (int r4 = 0; r4 < 4; ++r4) {
                int row = row0 + wr * (BM / 2) + mf * 16 + (l >> 4) * 4 + r4;
                float v = acc[mf][nf][r4] + bb;
                if (RELU) v = fmaxf(v, 0.f);
                C[(size_t)row * ldc + col] = f2bf(v);
            }
        }
}

// ============================================================================
// Windowed (banded) MHA, MFMA flash version (hardware-verified, unchanged).
// ============================================================================
__global__ __launch_bounds__(256) void wattn_kernel(
    const unsigned short* __restrict__ qkv,
    unsigned short* __restrict__ out,      // [B,S,512] bf16
    int min_key)
{
    const int n = blockIdx.x, h = blockIdx.y, b = blockIdx.z;
    const int t = threadIdx.x;
    const int w = t >> 6, l = t & 63;
    const int l4 = l >> 4, lm = l & 15;

    __shared__ __align__(16) unsigned short Ks[64 * 64];
    __shared__ __align__(16) unsigned short Vt[64 * 72];
    __shared__ __align__(16) unsigned short Ps[64 * 72];

    const int q0g = n * 64;
    const size_t base = (size_t)b * S_ * QKVLD;

    s16x8 qf[2];
    {
        const unsigned short* qrow =
            qkv + base + (size_t)(q0g + w * 16 + lm) * QKVLD + h * 64 + l4 * 8;
        qf[0] = *(const s16x8*)(qrow);
        qf[1] = *(const s16x8*)(qrow + 32);
    }

    float m[4], lsum[4];
    f32x4 oacc[4];
    #pragma unroll
    for (int e = 0; e < 4; ++e) {
        m[e] = -1e30f; lsum[e] = 0.f;
        oacc[e] = {0.f, 0.f, 0.f, 0.f};
    }

    const int lr = l >> 3, lc = l & 7;

    for (int c = 0; c < 5; ++c) {
        const int klo = q0g - 128 + c * 64;
        if (klo < 0 || klo >= S_) continue;
        __syncthreads();

        #pragma unroll
        for (int i = 0; i < 2; ++i) {
            int seg = w * 2 + i;
            int r = seg * 8 + lr;
            int kc = lc ^ (r & 7);
            gload_lds16(qkv + base + (size_t)(klo + r) * QKVLD + 512 + h * 64 + kc * 8,
                        (void*)(Ks + seg * 512));
        }
        {
            int jp = (t & 31) * 2, ds = (t >> 5) * 8;
            uint4 r0 = *(const uint4*)(qkv + base + (size_t)(klo + jp) * QKVLD + 1024 + h * 64 + ds);
            uint4 r1 = *(const uint4*)(qkv + base + (size_t)(klo + jp + 1) * QKVLD + 1024 + h * 64 + ds);
            const unsigned short* va = (const unsigned short*)&r0;
            const unsigned short* vb = (const unsigned short*)&r1;
            #pragma unroll
            for (int j = 0; j < 8; ++j)
                *(unsigned int*)(Vt + (ds + j) * 72 + jp) =
                    (unsigned int)va[j] | ((unsigned int)vb[j] << 16);
        }
        __syncthreads();

        f32x4 sf[4];
        #pragma unroll
        for (int nf = 0; nf < 4; ++nf) sf[nf] = {0.f, 0.f, 0.f, 0.f};
        #pragma unroll
        for (int kk = 0; kk < 2; ++kk)
            #pragma unroll
            for (int nf = 0; nf < 4; ++nf) {
                int r = nf * 16 + lm;
                int ch = (kk * 4 + l4) ^ (r & 7);
                s16x8 kf = *(const s16x8*)(Ks + r * 64 + ch * 8);
                sf[nf] = __builtin_amdgcn_mfma_f32_16x16x32_bf16(qf[kk], kf, sf[nf], 0, 0, 0);
            }

        #pragma unroll
        for (int r4 = 0; r4 < 4; ++r4) {
            const int qpos = q0g + w * 16 + l4 * 4 + r4;
            float sv[4];
            #pragma unroll
            for (int nf = 0; nf < 4; ++nf) {
                int kpos = klo + nf * 16 + lm;
                int rel = kpos - qpos;
                bool valid = (rel <= 128) & (rel >= -128) & (kpos >= min_key);
                sv[nf] = valid ? sf[nf][r4] * 0.125f : -1e9f;
            }
            float mx = fmaxf(fmaxf(sv[0], sv[1]), fmaxf(sv[2], sv[3]));
            #pragma unroll
            for (int st = 1; st < 16; st <<= 1)
                mx = fmaxf(mx, __shfl_xor(mx, st, 64));
            float mn = fmaxf(m[r4], mx);
            float sc = __expf(m[r4] - mn);
            float ps = 0.f;
            #pragma unroll
            for (int nf = 0; nf < 4; ++nf) {
                sv[nf] = __expf(sv[nf] - mn);
                ps += sv[nf];
            }
            #pragma unroll
            for (int st = 1; st < 16; st <<= 1)
                ps += __shfl_xor(ps, st, 64);
            lsum[r4] = lsum[r4] * sc + ps;
            m[r4] = mn;
            #pragma unroll
            for (int nf = 0; nf < 4; ++nf) oacc[nf][r4] *= sc;
            const int prow = w * 16 + l4 * 4 + r4;
            #pragma unroll
            for (int nf = 0; nf < 4; ++nf)
                Ps[prow * 72 + nf * 16 + lm] = f2bf(sv[nf]);
        }

        #pragma unroll
        for (int kk = 0; kk < 2; ++kk) {
            s16x8 pf = *(const s16x8*)(Ps + (w * 16 + lm) * 72 + l4 * 8 + kk * 32);
            #pragma unroll
            for (int nf = 0; nf < 4; ++nf) {
                s16x8 vf = *(const s16x8*)(Vt + (nf * 16 + lm) * 72 + l4 * 8 + kk * 32);
                oacc[nf] = __builtin_amdgcn_mfma_f32_16x16x32_bf16(pf, vf, oacc[nf], 0, 0, 0);
            }
        }
    }

    #pragma unroll
    for (int r4 = 0; r4 < 4; ++r4) {
        float inv = 1.f / lsum[r4];
        size_t row = (size_t)b * S_ + q0g + w * 16 + l4 * 4 + r4;
        #pragma unroll
        for (int nf = 0; nf < 4; ++nf)
            out[row * H_ + h * 64 + nf * 16 + lm] = f2bf(oacc[nf][r4] * inv);
    }
}

// ============================================================================
// cls q projection, wave-per-output: q_cls[b,j] = xb[b,0,:].WqkvT_cls[j,:] + bq
// 1024 outputs, 4 waves/block -> 256 blocks. Contiguous bf16 row reads.
// ============================================================================
__global__ __launch_bounds__(256) void qcls_kernel(
    const unsigned short* __restrict__ xb, const unsigned short* __restrict__ WqkvT,
    const float* __restrict__ bqkv, float* __restrict__ q_cls)
{
    int gw = blockIdx.x * 4 + (threadIdx.x >> 6);   // 0..1023
    int l = threadIdx.x & 63;
    int b = gw >> 9, j = gw & 511;
    s16x8 xv = *(const s16x8*)(xb + (size_t)b * S_ * H_ + l * 8);
    s16x8 wv = *(const s16x8*)(WqkvT + (size_t)j * 512 + l * 8);
    float s = 0.f;
    #pragma unroll
    for (int e = 0; e < 8; ++e)
        s += bf2f((unsigned short)xv[e]) * bf2f((unsigned short)wv[e]);
    #pragma unroll
    for (int st = 1; st < 64; st <<= 1) s += __shfl_xor(s, st, 64);
    if (l == 0) q_cls[gw] = s + bqkv[j];
}

// ============================================================================
// cls attention, flash-split part: grid (16 bh, CCH chunks of 512 keys).
// Per chunk: local max m_c, l_c = sum exp, o_c[64] = sum p*v (unnormalized).
// part[(bh*CCH+ck)*66] = {o_c[0..63], m_c, l_c}
// ============================================================================
__global__ __launch_bounds__(256) void cls_attn_part(
    const float* __restrict__ q_cls, const unsigned short* __restrict__ qkv,
    float* __restrict__ part)
{
    const int bh = blockIdx.x, ck = blockIdx.y;
    const int b = bh >> 3, h = bh & 7;
    const int t = threadIdx.x;
    __shared__ float sQ[64];
    __shared__ float sP[512];
    __shared__ float red[256];
    __shared__ float pacc[16][64];
    if (t < 64) sQ[t] = q_cls[b * H_ + h * 64 + t] * 0.125f;
    __syncthreads();
    const size_t base = (size_t)b * S_ * QKVLD;
    const int j0 = ck * 512;

    float sv[2], smax = -1e30f;
    #pragma unroll
    for (int i = 0; i < 2; ++i) {
        int j = j0 + t + i * 256;
        const unsigned short* kr = qkv + base + (size_t)j * QKVLD + 512 + h * 64;
        float s = 0.f;
        #pragma unroll
        for (int d8 = 0; d8 < 8; ++d8) {
            uint4 raw = *(const uint4*)(kr + d8 * 8);
            const float* q = &sQ[d8 * 8];
            s = fmaf(q[0], bflo(raw.x), s); s = fmaf(q[1], bfhi(raw.x), s);
            s = fmaf(q[2], bflo(raw.y), s); s = fmaf(q[3], bfhi(raw.y), s);
            s = fmaf(q[4], bflo(raw.z), s); s = fmaf(q[5], bfhi(raw.z), s);
            s = fmaf(q[6], bflo(raw.w), s); s = fmaf(q[7], bfhi(raw.w), s);
        }
        sv[i] = s;
        smax = fmaxf(smax, s);
    }
    red[t] = smax; __syncthreads();
    for (int st = 128; st > 0; st >>= 1) {
        if (t < st) red[t] = fmaxf(red[t], red[t + st]);
        __syncthreads();
    }
    float mc = red[0];
    __syncthreads();
    float ls = 0.f;
    #pragma unroll
    for (int i = 0; i < 2; ++i) {
        float p = __expf(sv[i] - mc);
        sP[t + i * 256] = p;
        ls += p;
    }
    red[t] = ls; __syncthreads();
    for (int st = 128; st > 0; st >>= 1) {
        if (t < st) red[t] += red[t + st];
        __syncthreads();
    }
    float lc = red[0];

    // PV partial: group g = 32 keys, lane d4 = 4 dims
    int g = t >> 4, d4 = t & 15;
    float4 acc; acc.x = 0.f; acc.y = 0.f; acc.z = 0.f; acc.w = 0.f;
    for (int j = g * 32; j < g * 32 + 32; ++j) {
        float p = sP[j];
        uint2 raw = *(const uint2*)(qkv + base + (size_t)(j0 + j) * QKVLD + 1024 + h * 64 + d4 * 4);
        acc.x = fmaf(p, bflo(raw.x), acc.x); acc.y = fmaf(p, bfhi(raw.x), acc.y);
        acc.z = fmaf(p, bflo(raw.y), acc.z); acc.w = fmaf(p, bfhi(raw.y), acc.w);
    }
    *(float4*)&pacc[g][d4 * 4] = acc;
    __syncthreads();
    float* op = part + (size_t)(bh * CCH + ck) * 66;
    if (t < 64) {
        float r = 0.f;
        #pragma unroll
        for (int g2 = 0; g2 < 16; ++g2) r += pacc[g2][t];
        op[t] = r;
    }
    if (t == 64) op[64] = mc;
    if (t == 65) op[65] = lc;
}

// ============================================================================
// cls attention reduce: merge CCH chunks via logsumexp -> gpre[b,512] fp32
// ============================================================================
__global__ __launch_bounds__(64) void cls_attn_reduce(
    const float* __restrict__ part, float* __restrict__ gpre)
{
    int bh = blockIdx.x, t = threadIdx.x;   // 64 threads = dims
    int b = bh >> 3, h = bh & 7;
    const float* pp = part + (size_t)bh * CCH * 66;
    float M = -1e30f;
    #pragma unroll
    for (int c = 0; c < CCH; ++c) M = fmaxf(M, pp[c * 66 + 64]);
    float L = 0.f, o = 0.f;
    #pragma unroll
    for (int c = 0; c < CCH; ++c) {
        float wgt = __expf(pp[c * 66 + 64] - M);
        L += pp[c * 66 + 65] * wgt;
        o += pp[c * 66 + t] * wgt;
    }
    gpre[b * H_ + h * 64 + t] = o / L;
}

// ============================================================================
// cls Wo projection + LogN, wave-per-output (WoT_cls bf16 contiguous rows)
// ============================================================================
__global__ __launch_bounds__(256) void clsproj_kernel(
    const float* __restrict__ gpre, const unsigned short* __restrict__ WoT,
    const float* __restrict__ bo, const float* __restrict__ logn,
    unsigned short* __restrict__ attended)
{
    int gw = blockIdx.x * 4 + (threadIdx.x >> 6);
    int l = threadIdx.x & 63;
    int b = gw >> 9, j = gw & 511;
    const float* gr = gpre + b * H_ + l * 8;
    s16x8 wv = *(const s16x8*)(WoT + (size_t)j * 512 + l * 8);
    float s = 0.f;
    #pragma unroll
    for (int e = 0; e < 8; ++e) s += gr[e] * bf2f((unsigned short)wv[e]);
    #pragma unroll
    for (int st = 1; st < 64; st <<= 1) s += __shfl_xor(s, st, 64);
    if (l == 0) attended[(size_t)b * S_ * H_ + j] = f2bf((s + bo[j]) * logn[0]);
}

// ============================================================================
// classifier: out[r,l] = seq[r,:] @ Wc[:,l] + bc[l]  (L=17, seq bf16, out fp32)
// ============================================================================
__global__ __launch_bounds__(256) void logits_kernel(
    const unsigned short* __restrict__ seq, const float* __restrict__ Wc,
    const float* __restrict__ bc, float* __restrict__ out)
{
    __shared__ float sWc[17][516];
    for (int i = threadIdx.x; i < 512 * 17; i += 256) {
        int d = i / 17, lcol = i % 17;
        sWc[lcol][d] = Wc[i];
    }
    __syncthreads();
    int idx = blockIdx.x * 256 + threadIdx.x;
    if (idx >= M_ * 17) return;
    int r = idx / 17, lcol = idx % 17;
    const unsigned short* sr = seq + (size_t)r * H_;
    float s = bc[lcol];
    for (int d8 = 0; d8 < 64; ++d8) {
        uint4 raw = *(const uint4*)(sr + d8 * 8);
        const float* wr = &sWc[lcol][d8 * 8];
        s = fmaf(bflo(raw.x), wr[0], s); s = fmaf(bfhi(raw.x), wr[1], s);
        s = fmaf(bflo(raw.y), wr[2], s); s = fmaf(bfhi(raw.y), wr[3], s);
        s = fmaf(bflo(raw.z), wr[4], s); s = fmaf(bfhi(raw.z), wr[5], s);
        s = fmaf(bflo(raw.w), wr[6], s); s = fmaf(bfhi(raw.w), wr[7], s);
    }
    out[idx] = s;
}

// ============================================================================
extern "C" void kernel_launch(void* const* d_in, const int* in_sizes, int n_in,
                              void* d_out, int out_size, void* d_ws, size_t ws_size,
                              hipStream_t stream) {
    const float* x        = (const float*)d_in[0];
    const float* Wqkv_cls = (const float*)d_in[1];
    const float* bqkv_cls = (const float*)d_in[2];
    const float* Wo_cls   = (const float*)d_in[3];
    const float* bo_cls   = (const float*)d_in[4];
    const float* Wqkv_loc = (const float*)d_in[5];
    const float* bqkv_loc = (const float*)d_in[6];
    const float* Wo_loc   = (const float*)d_in[7];
    const float* bo_loc   = (const float*)d_in[8];
    const float* logn     = (const float*)d_in[9];
    const float* Wqkv_h   = (const float*)d_in[10];
    const float* bqkv_h   = (const float*)d_in[11];
    const float* Wo_h     = (const float*)d_in[12];
    const float* bo_h     = (const float*)d_in[13];
    const float* Wqkv_v   = (const float*)d_in[14];
    const float* bqkv_v   = (const float*)d_in[15];
    const float* Wo_v     = (const float*)d_in[16];
    const float* bo_v     = (const float*)d_in[17];
    const float* W1       = (const float*)d_in[18];
    const float* b1       = (const float*)d_in[19];
    const float* W2       = (const float*)d_in[20];
    const float* b2       = (const float*)d_in[21];
    const float* Wc       = (const float*)d_in[22];
    const float* bc       = (const float*)d_in[23];
    float* out = (float*)d_out;

    // workspace layout in bf16 (unsigned short) elements
    unsigned short* wsu = (unsigned short*)d_ws;
    unsigned short* xb        = wsu;                 //  4,194,304 used
    unsigned short* qkv       = wsu +  8388608;      // 12,582,912
    unsigned short* attnout   = wsu + 20971520;      //  4,194,304
    unsigned short* attended  = wsu + 25165824;      //  4,194,304
    unsigned short* combined  = wsu + 29360128;      //  8,388,608
    unsigned short* hidden    = wsu + 37748736;      //  4,194,304
    unsigned short* seq       = wsu + 41943040;      //  4,194,304
    unsigned short* WqkvT_cls = wsu + 46137344;      //    786,432 each
    unsigned short* WqkvT_loc = wsu + 46923776;
    unsigned short* WqkvT_h   = wsu + 47710208;
    unsigned short* WqkvT_v   = wsu + 48496640;
    unsigned short* WoT_loc   = wsu + 49283072;      //    262,144 each
    unsigned short* WoT_h     = wsu + 49545216;
    unsigned short* WoT_v     = wsu + 49807360;
    unsigned short* W2T       = wsu + 50069504;
    unsigned short* W1T       = wsu + 50331648;      //    524,288
    unsigned short* WoT_cls   = wsu + 50855936;      //    262,144
    float* q_cls              = (float*)(wsu + 51118080);   // 1024
    float* gpre               = q_cls + 1024;               // 1024
    float* part               = gpre + 1024;                // 16*CCH*66 = 8448

    dim3 blk(256);

    // --- conversions ---
    cvt_kernel<<<dim3(2048), blk, 0, stream>>>(x, xb, 524288);
    wtrans_kernel<<<dim3(48, 16, 4), blk, 0, stream>>>(
        Wqkv_cls, Wqkv_loc, Wqkv_h, Wqkv_v,
        WqkvT_cls, WqkvT_loc, WqkvT_h, WqkvT_v, 512, 1536);
    wtrans_kernel<<<dim3(16, 16, 4), blk, 0, stream>>>(
        Wo_loc, Wo_h, Wo_v, W2, WoT_loc, WoT_h, WoT_v, W2T, 512, 512);
    wtrans_kernel<<<dim3(16, 32, 1), blk, 0, stream>>>(
        W1, W1, W1, W1, W1T, W1T, W1T, W1T, 1024, 512);
    wtrans_kernel<<<dim3(16, 16, 1), blk, 0, stream>>>(
        Wo_cls, Wo_cls, Wo_cls, Wo_cls, WoT_cls, WoT_cls, WoT_cls, WoT_cls, 512, 512);

    // --- cls path ---
    mgemm_kernel<128, 0><<<dim3(8, 64), blk, 0, stream>>>(
        xb, 512, WqkvT_cls + 512 * 512, 512, bqkv_cls + 512, qkv + 512, 1536, 512);
    qcls_kernel<<<dim3(256), blk, 0, stream>>>(xb, WqkvT_cls, bqkv_cls, q_cls);
    cls_attn_part<<<dim3(16, CCH), blk, 0, stream>>>(q_cls, qkv, part);
    cls_attn_reduce<<<dim3(16), dim3(64), 0, stream>>>(part, gpre);

    // --- loc attention ---
    mgemm_kernel<128, 0><<<dim3(12, 64), blk, 0, stream>>>(
        xb, 512, WqkvT_loc, 512, bqkv_loc, qkv, 1536, 512);
    wattn_kernel<<<dim3(64, 8, 2), blk, 0, stream>>>(qkv, attnout, 1);
    mgemm_kernel<64, 0><<<dim3(4, 128), blk, 0, stream>>>(
        attnout, 512, WoT_loc, 512, bo_loc, attended, 512, 512);
    clsproj_kernel<<<dim3(256), blk, 0, stream>>>(gpre, WoT_cls, bo_cls, logn, attended);

    // --- h attention ---
    mgemm_kernel<128, 0><<<dim3(12, 64), blk, 0, stream>>>(
        attended, 512, WqkvT_h, 512, bqkv_h, qkv, 1536, 512);
    wattn_kernel<<<dim3(64, 8, 2), blk, 0, stream>>>(qkv, attnout, 0);
    mgemm_kernel<64, 0><<<dim3(4, 128), blk, 0, stream>>>(
        attnout, 512, WoT_h, 512, bo_h, combined, 1024, 512);

    // --- v attention ---
    mgemm_kernel<128, 0><<<dim3(12, 64), blk, 0, stream>>>(
        attended, 512, WqkvT_v, 512, bqkv_v, qkv, 1536, 512);
    wattn_kernel<<<dim3(64, 8, 2), blk, 0, stream>>>(qkv, attnout, 0);
    mgemm_kernel<64, 0><<<dim3(4, 128), blk, 0, stream>>>(
        attnout, 512, WoT_v, 512, bo_v, combined + 512, 1024, 512);

    // --- MLP + classifier ---
    mgemm_kernel<64, 1><<<dim3(4, 128), blk, 0, stream>>>(
        combined, 1024, W1T, 1024, b1, hidden, 512, 1024);
    mgemm_kernel<64, 0><<<dim3(4, 128), blk, 0, stream>>>(
        hidden, 512, W2T, 512, b2, seq, 512, 512);
    logits_kernel<<<dim3((M_ * 17 + 255) / 256), blk, 0, stream>>>(seq, Wc, bc, out);
}

// Round 10
// 336.436 us; speedup vs baseline: 4.7295x; 1.0652x over previous
//
#include <hip/hip_runtime.h>

#define S_ 4096
#define H_ 512
#define M_ 8192
#define CCH 8   // cls-attention key chunks (512 keys each)

typedef __attribute__((ext_vector_type(8))) short s16x8;   // 8 bf16 = 4 VGPR
typedef __attribute__((ext_vector_type(4))) float f32x4;   // MFMA acc frag

__device__ __forceinline__ float bflo(unsigned int w) { return __uint_as_float(w << 16); }
__device__ __forceinline__ float bfhi(unsigned int w) { return __uint_as_float(w & 0xFFFF0000u); }
__device__ __forceinline__ float bf2f(unsigned short u) { return __uint_as_float(((unsigned int)u) << 16); }
__device__ __forceinline__ unsigned short f2bf(float f) {   // RNE
    unsigned int x = __float_as_uint(f);
    return (unsigned short)((x + 0x7FFFu + ((x >> 16) & 1u)) >> 16);
}
__device__ __forceinline__ void gload_lds16(const void* g, void* l) {
    __builtin_amdgcn_global_load_lds(
        (const __attribute__((address_space(1))) unsigned int*)g,
        (__attribute__((address_space(3))) unsigned int*)l, 16, 0, 0);
}

// ============================================================================
// fp32 -> bf16 cast (x input), 8 elts/thread.  n8 = total_elements / 8.
// ============================================================================
__global__ __launch_bounds__(256) void cvt_kernel(
    const float* __restrict__ in, unsigned short* __restrict__ out, int n8)
{
    int i = blockIdx.x * 256 + threadIdx.x;
    if (i >= n8) return;
    float4 a = *(const float4*)(in + (size_t)i * 8);
    float4 b = *(const float4*)(in + (size_t)i * 8 + 4);
    uint4 pk;
    pk.x = (unsigned int)f2bf(a.x) | ((unsigned int)f2bf(a.y) << 16);
    pk.y = (unsigned int)f2bf(a.z) | ((unsigned int)f2bf(a.w) << 16);
    pk.z = (unsigned int)f2bf(b.x) | ((unsigned int)f2bf(b.y) << 16);
    pk.w = (unsigned int)f2bf(b.z) | ((unsigned int)f2bf(b.w) << 16);
    *(uint4*)(out + (size_t)i * 8) = pk;
}

// ============================================================================
// Weight transpose + cast: fp32 [K][N] -> bf16 [N][K]; up to 5 matrices via z.
// ============================================================================
__global__ __launch_bounds__(256) void wtrans_kernel(
    const float* __restrict__ p0, const float* __restrict__ p1,
    const float* __restrict__ p2, const float* __restrict__ p3,
    const float* __restrict__ p4,
    unsigned short* o0, unsigned short* o1,
    unsigned short* o2, unsigned short* o3, unsigned short* o4,
    int K, int N)
{
    const float* in; unsigned short* out;
    switch (blockIdx.z) {
        case 0:  in = p0; out = o0; break;
        case 1:  in = p1; out = o1; break;
        case 2:  in = p2; out = o2; break;
        case 3:  in = p3; out = o3; break;
        default: in = p4; out = o4; break;
    }
    __shared__ float tile[32][33];
    int n0 = blockIdx.x * 32, k0 = blockIdx.y * 32;
    int tx = threadIdx.x & 31, ty = threadIdx.x >> 5;   // 32 x 8
    #pragma unroll
    for (int i = 0; i < 4; ++i) {
        int k = k0 + ty * 4 + i;
        tile[ty * 4 + i][tx] = in[(size_t)k * N + n0 + tx];
    }
    __syncthreads();
    #pragma unroll
    for (int i = 0; i < 4; ++i) {
        int n = n0 + ty * 4 + i;
        out[(size_t)n * K + k0 + tx] = f2bf(tile[tx][ty * 4 + i]);
    }
}

// ============================================================================
// bf16 MFMA GEMM (inner loop hardware-verified, unchanged).
// New: (a) column-split bias  bb = col<nsplit ? bias[col] : biasB[col-nsplit]
//      (b) dual-z launches: blockIdx.z offsets A/Bt/C by az/bz/cz elems and
//          selects biasB as the bias for z>0 (nsplit then covers all cols).
// ============================================================================
template<int BM, int RELU>
__global__ __launch_bounds__(256) void mgemm_kernel(
    const unsigned short* __restrict__ A, int lda,
    const unsigned short* __restrict__ Bt, int ldb,
    const float* __restrict__ bias, const float* __restrict__ biasB, int nsplit,
    unsigned short* __restrict__ C, int ldc, int K,
    size_t az, size_t bz, size_t cz)
{
    constexpr int MF = BM / 32;
    constexpr int ASEG = BM / 32;
    __shared__ __align__(16) unsigned short As[BM * 64];
    __shared__ __align__(16) unsigned short Bs[128 * 64];
    const int z = blockIdx.z;
    A  += (size_t)z * az;
    Bt += (size_t)z * bz;
    C  += (size_t)z * cz;
    if (z > 0) bias = biasB;
    const int t = threadIdx.x;
    const int w = t >> 6, l = t & 63;
    const int wr = w >> 1, wc = w & 1;
    const int row0 = blockIdx.y * BM, col0 = blockIdx.x * 128;
    const int lr = l >> 3;
    const int lc = l & 7;

    f32x4 acc[MF][4];
    #pragma unroll
    for (int i = 0; i < MF; ++i)
        #pragma unroll
        for (int j = 0; j < 4; ++j) acc[i][j] = {0.f, 0.f, 0.f, 0.f};

    for (int k0 = 0; k0 < K; k0 += 64) {
        __syncthreads();
        #pragma unroll
        for (int i = 0; i < ASEG; ++i) {
            int seg = w * ASEG + i;
            int r = seg * 8 + lr;
            int kc = lc ^ (r & 7);
            gload_lds16(A + (size_t)(row0 + r) * lda + k0 + kc * 8,
                        (void*)(As + seg * 512));
        }
        #pragma unroll
        for (int i = 0; i < 4; ++i) {
            int seg = w * 4 + i;
            int r = seg * 8 + lr;
            int kc = lc ^ (r & 7);
            gload_lds16(Bt + (size_t)(col0 + r) * ldb + k0 + kc * 8,
                        (void*)(Bs + seg * 512));
        }
        __syncthreads();

        s16x8 af[MF][2], bf[4][2];
        #pragma unroll
        for (int mf = 0; mf < MF; ++mf)
            #pragma unroll
            for (int kk = 0; kk < 2; ++kk) {
                int r = wr * (BM / 2) + mf * 16 + (l & 15);
                int ch = (kk * 4 + (l >> 4)) ^ (r & 7);
                af[mf][kk] = *(const s16x8*)(As + r * 64 + ch * 8);
            }
        #pragma unroll
        for (int nf = 0; nf < 4; ++nf)
            #pragma unroll
            for (int kk = 0; kk < 2; ++kk) {
                int r = wc * 64 + nf * 16 + (l & 15);
                int ch = (kk * 4 + (l >> 4)) ^ (r & 7);
                bf[nf][kk] = *(const s16x8*)(Bs + r * 64 + ch * 8);
            }
        #pragma unroll
        for (int kk = 0; kk < 2; ++kk)
            #pragma unroll
            for (int mf = 0; mf < MF; ++mf)
                #pragma unroll
                for (int nf = 0; nf < 4; ++nf)
                    acc[mf][nf] = __builtin_amdgcn_mfma_f32_16x16x32_bf16(
                        af[mf][kk], bf[nf][kk], acc[mf][nf], 0, 0, 0);
    }

    #pragma unroll
    for (int mf = 0; mf < MF; ++mf)
        #pragma unroll
        for (int nf = 0; nf < 4; ++nf) {
            int col = col0 + wc * 64 + nf * 16 + (l & 15);
            float bb = (col < nsplit) ? bias[col] : biasB[col - nsplit];
            #pragma unroll
            for (int r4 = 0; r4 < 4; ++r4) {
                int row = row0 + wr * (BM / 2) + mf * 16 + (l >> 4) * 4 + r4;
                float v = acc[mf][nf][r4] + bb;
                if (RELU) v = fmaxf(v, 0.f);
                C[(size_t)row * ldc + col] = f2bf(v);
            }
        }
}

// ============================================================================
// Windowed (banded) MHA, MFMA flash version (inner loops hardware-verified).
// Parameterized: qkv row-stride qld; q columns start at qbase + br*1536
// (k = +512, v = +1024); blockIdx.z = br*2 + b; out (ld 512) += br*brstride.
// need_mask: chunks 1..3 are provably unmasked unless klo < min_key.
// ============================================================================
__global__ __launch_bounds__(256) void wattn_kernel(
    const unsigned short* __restrict__ qkv, int qld, int qbase,
    unsigned short* __restrict__ out, size_t brstride, int min_key)
{
    const int n = blockIdx.x, h = blockIdx.y;
    const int z = blockIdx.z, br = z >> 1, b = z & 1;
    const int t = threadIdx.x;
    const int w = t >> 6, l = t & 63;
    const int l4 = l >> 4, lm = l & 15;

    __shared__ __align__(16) unsigned short Ks[64 * 64];
    __shared__ __align__(16) unsigned short Vt[64 * 72];
    __shared__ __align__(16) unsigned short Ps[64 * 72];

    const int q0g = n * 64;
    const int qcol = qbase + br * 1536;
    const size_t base = (size_t)b * S_ * qld;
    out += (size_t)br * brstride;

    s16x8 qf[2];
    {
        const unsigned short* qrow =
            qkv + base + (size_t)(q0g + w * 16 + lm) * qld + qcol + h * 64 + l4 * 8;
        qf[0] = *(const s16x8*)(qrow);
        qf[1] = *(const s16x8*)(qrow + 32);
    }

    float m[4], lsum[4];
    f32x4 oacc[4];
    #pragma unroll
    for (int e = 0; e < 4; ++e) {
        m[e] = -1e30f; lsum[e] = 0.f;
        oacc[e] = {0.f, 0.f, 0.f, 0.f};
    }

    const int lr = l >> 3, lc = l & 7;

    for (int c = 0; c < 5; ++c) {
        const int klo = q0g - 128 + c * 64;
        if (klo < 0 || klo >= S_) continue;
        const bool need_mask = (c == 0) | (c == 4) | (klo < min_key);
        __syncthreads();

        #pragma unroll
        for (int i = 0; i < 2; ++i) {
            int seg = w * 2 + i;
            int r = seg * 8 + lr;
            int kc = lc ^ (r & 7);
            gload_lds16(qkv + base + (size_t)(klo + r) * qld + qcol + 512 + h * 64 + kc * 8,
                        (void*)(Ks + seg * 512));
        }
        {
            int jp = (t & 31) * 2, ds = (t >> 5) * 8;
            uint4 r0 = *(const uint4*)(qkv + base + (size_t)(klo + jp) * qld + qcol + 1024 + h * 64 + ds);
            uint4 r1 = *(const uint4*)(qkv + base + (size_t)(klo + jp + 1) * qld + qcol + 1024 + h * 64 + ds);
            const unsigned short* va = (const unsigned short*)&r0;
            const unsigned short* vb = (const unsigned short*)&r1;
            #pragma unroll
            for (int j = 0; j < 8; ++j)
                *(unsigned int*)(Vt + (ds + j) * 72 + jp) =
                    (unsigned int)va[j] | ((unsigned int)vb[j] << 16);
        }
        __syncthreads();

        f32x4 sf[4];
        #pragma unroll
        for (int nf = 0; nf < 4; ++nf) sf[nf] = {0.f, 0.f, 0.f, 0.f};
        #pragma unroll
        for (int kk = 0; kk < 2; ++kk)
            #pragma unroll
            for (int nf = 0; nf < 4; ++nf) {
                int r = nf * 16 + lm;
                int ch = (kk * 4 + l4) ^ (r & 7);
                s16x8 kf = *(const s16x8*)(Ks + r * 64 + ch * 8);
                sf[nf] = __builtin_amdgcn_mfma_f32_16x16x32_bf16(qf[kk], kf, sf[nf], 0, 0, 0);
            }

        #pragma unroll
        for (int r4 = 0; r4 < 4; ++r4) {
            const int qpos = q0g + w * 16 + l4 * 4 + r4;
            float sv[4];
            #pragma unroll
            for (int nf = 0; nf < 4; ++nf) sv[nf] = sf[nf][r4] * 0.125f;
            if (need_mask) {
                #pragma unroll
                for (int nf = 0; nf < 4; ++nf) {
                    int kpos = klo + nf * 16 + lm;
                    int rel = kpos - qpos;
                    bool valid = (rel <= 128) & (rel >= -128) & (kpos >= min_key);
                    if (!valid) sv[nf] = -1e9f;
                }
            }
            float mx = fmaxf(fmaxf(sv[0], sv[1]), fmaxf(sv[2], sv[3]));
            #pragma unroll
            for (int st = 1; st < 16; st <<= 1)
                mx = fmaxf(mx, __shfl_xor(mx, st, 64));
            float mn = fmaxf(m[r4], mx);
            float sc = __expf(m[r4] - mn);
            float ps = 0.f;
            #pragma unroll
            for (int nf = 0; nf < 4; ++nf) {
                sv[nf] = __expf(sv[nf] - mn);
                ps += sv[nf];
            }
            #pragma unroll
            for (int st = 1; st < 16; st <<= 1)
                ps += __shfl_xor(ps, st, 64);
            lsum[r4] = lsum[r4] * sc + ps;
            m[r4] = mn;
            #pragma unroll
            for (int nf = 0; nf < 4; ++nf) oacc[nf][r4] *= sc;
            const int prow = w * 16 + l4 * 4 + r4;
            #pragma unroll
            for (int nf = 0; nf < 4; ++nf)
                Ps[prow * 72 + nf * 16 + lm] = f2bf(sv[nf]);
        }

        #pragma unroll
        for (int kk = 0; kk < 2; ++kk) {
            s16x8 pf = *(const s16x8*)(Ps + (w * 16 + lm) * 72 + l4 * 8 + kk * 32);
            #pragma unroll
            for (int nf = 0; nf < 4; ++nf) {
                s16x8 vf = *(const s16x8*)(Vt + (nf * 16 + lm) * 72 + l4 * 8 + kk * 32);
                oacc[nf] = __builtin_amdgcn_mfma_f32_16x16x32_bf16(pf, vf, oacc[nf], 0, 0, 0);
            }
        }
    }

    #pragma unroll
    for (int r4 = 0; r4 < 4; ++r4) {
        float inv = 1.f / lsum[r4];
        size_t row = (size_t)b * S_ + q0g + w * 16 + l4 * 4 + r4;
        #pragma unroll
        for (int nf = 0; nf < 4; ++nf)
            out[row * 512 + h * 64 + nf * 16 + lm] = f2bf(oacc[nf][r4] * inv);
    }
}

// ============================================================================
// cls q projection, wave-per-output (verified).
// ============================================================================
__global__ __launch_bounds__(256) void qcls_kernel(
    const unsigned short* __restrict__ xb, const unsigned short* __restrict__ WqkvT,
    const float* __restrict__ bqkv, float* __restrict__ q_cls)
{
    int gw = blockIdx.x * 4 + (threadIdx.x >> 6);   // 0..1023
    int l = threadIdx.x & 63;
    int b = gw >> 9, j = gw & 511;
    s16x8 xv = *(const s16x8*)(xb + (size_t)b * S_ * H_ + l * 8);
    s16x8 wv = *(const s16x8*)(WqkvT + (size_t)j * 512 + l * 8);
    float s = 0.f;
    #pragma unroll
    for (int e = 0; e < 8; ++e)
        s += bf2f((unsigned short)xv[e]) * bf2f((unsigned short)wv[e]);
    #pragma unroll
    for (int st = 1; st < 64; st <<= 1) s += __shfl_xor(s, st, 64);
    if (l == 0) q_cls[gw] = s + bqkv[j];
}

// ============================================================================
// cls attention flash-split part (verified): reads qkvA (ld 2560, K at col 0,
// V at col 512). part[(bh*CCH+ck)*66] = {o_c[0..63], m_c, l_c}
// ============================================================================
__global__ __launch_bounds__(256) void cls_attn_part(
    const float* __restrict__ q_cls, const unsigned short* __restrict__ qkv,
    float* __restrict__ part)
{
    const int bh = blockIdx.x, ck = blockIdx.y;
    const int b = bh >> 3, h = bh & 7;
    const int t = threadIdx.x;
    __shared__ float sQ[64];
    __shared__ float sP[512];
    __shared__ float red[256];
    __shared__ float pacc[16][64];
    if (t < 64) sQ[t] = q_cls[b * H_ + h * 64 + t] * 0.125f;
    __syncthreads();
    const size_t base = (size_t)b * S_ * 2560;
    const int j0 = ck * 512;

    float sv[2], smax = -1e30f;
    #pragma unroll
    for (int i = 0; i < 2; ++i) {
        int j = j0 + t + i * 256;
        const unsigned short* kr = qkv + base + (size_t)j * 2560 + h * 64;
        float s = 0.f;
        #pragma unroll
        for (int d8 = 0; d8 < 8; ++d8) {
            uint4 raw = *(const uint4*)(kr + d8 * 8);
            const float* q = &sQ[d8 * 8];
            s = fmaf(q[0], bflo(raw.x), s); s = fmaf(q[1], bfhi(raw.x), s);
            s = fmaf(q[2], bflo(raw.y), s); s = fmaf(q[3], bfhi(raw.y), s);
            s = fmaf(q[4], bflo(raw.z), s); s = fmaf(q[5], bfhi(raw.z), s);
            s = fmaf(q[6], bflo(raw.w), s); s = fmaf(q[7], bfhi(raw.w), s);
        }
        sv[i] = s;
        smax = fmaxf(smax, s);
    }
    red[t] = smax; __syncthreads();
    for (int st = 128; st > 0; st >>= 1) {
        if (t < st) red[t] = fmaxf(red[t], red[t + st]);
        __syncthreads();
    }
    float mc = red[0];
    __syncthreads();
    float ls = 0.f;
    #pragma unroll
    for (int i = 0; i < 2; ++i) {
        float p = __expf(sv[i] - mc);
        sP[t + i * 256] = p;
        ls += p;
    }
    red[t] = ls; __syncthreads();
    for (int st = 128; st > 0; st >>= 1) {
        if (t < st) red[t] += red[t + st];
        __syncthreads();
    }
    float lc = red[0];

    int g = t >> 4, d4 = t & 15;
    float4 acc; acc.x = 0.f; acc.y = 0.f; acc.z = 0.f; acc.w = 0.f;
    for (int j = g * 32; j < g * 32 + 32; ++j) {
        float p = sP[j];
        uint2 raw = *(const uint2*)(qkv + base + (size_t)(j0 + j) * 2560 + 512 + h * 64 + d4 * 4);
        acc.x = fmaf(p, bflo(raw.x), acc.x); acc.y = fmaf(p, bfhi(raw.x), acc.y);
        acc.z = fmaf(p, bflo(raw.y), acc.z); acc.w = fmaf(p, bfhi(raw.y), acc.w);
    }
    *(float4*)&pacc[g][d4 * 4] = acc;
    __syncthreads();
    float* op = part + (size_t)(bh * CCH + ck) * 66;
    if (t < 64) {
        float r = 0.f;
        #pragma unroll
        for (int g2 = 0; g2 < 16; ++g2) r += pacc[g2][t];
        op[t] = r;
    }
    if (t == 64) op[64] = mc;
    if (t == 65) op[65] = lc;
}

// ============================================================================
// cls attention reduce (verified): merge CCH chunks -> gpre[b,512] fp32
// ============================================================================
__global__ __launch_bounds__(64) void cls_attn_reduce(
    const float* __restrict__ part, float* __restrict__ gpre)
{
    int bh = blockIdx.x, t = threadIdx.x;
    int b = bh >> 3, h = bh & 7;
    const float* pp = part + (size_t)bh * CCH * 66;
    float M = -1e30f;
    #pragma unroll
    for (int c = 0; c < CCH; ++c) M = fmaxf(M, pp[c * 66 + 64]);
    float L = 0.f, o = 0.f;
    #pragma unroll
    for (int c = 0; c < CCH; ++c) {
        float wgt = __expf(pp[c * 66 + 64] - M);
        L += pp[c * 66 + 65] * wgt;
        o += pp[c * 66 + t] * wgt;
    }
    gpre[b * H_ + h * 64 + t] = o / L;
}

// ============================================================================
// cls Wo projection + LogN, wave-per-output (verified)
// ============================================================================
__global__ __launch_bounds__(256) void clsproj_kernel(
    const float* __restrict__ gpre, const unsigned short* __restrict__ WoT,
    const float* __restrict__ bo, const float* __restrict__ logn,
    unsigned short* __restrict__ attended)
{
    int gw = blockIdx.x * 4 + (threadIdx.x >> 6);
    int l = threadIdx.x & 63;
    int b = gw >> 9, j = gw & 511;
    const float* gr = gpre + b * H_ + l * 8;
    s16x8 wv = *(const s16x8*)(WoT + (size_t)j * 512 + l * 8);
    float s = 0.f;
    #pragma unroll
    for (int e = 0; e < 8; ++e) s += gr[e] * bf2f((unsigned short)wv[e]);
    #pragma unroll
    for (int st = 1; st < 64; st <<= 1) s += __shfl_xor(s, st, 64);
    if (l == 0) attended[(size_t)b * S_ * H_ + j] = f2bf((s + bo[j]) * logn[0]);
}

// ============================================================================
// classifier (verified): out[r,l] = seq[r,:] @ Wc[:,l] + bc[l]
// ============================================================================
__global__ __launch_bounds__(256) void logits_kernel(
    const unsigned short* __restrict__ seq, const float* __restrict__ Wc,
    const float* __restrict__ bc, float* __restrict__ out)
{
    __shared__ float sWc[17][516];
    for (int i = threadIdx.x; i < 512 * 17; i += 256) {
        int d = i / 17, lcol = i % 17;
        sWc[lcol][d] = Wc[i];
    }
    __syncthreads();
    int idx = blockIdx.x * 256 + threadIdx.x;
    if (idx >= M_ * 17) return;
    int r = idx / 17, lcol = idx % 17;
    const unsigned short* sr = seq + (size_t)r * H_;
    float s = bc[lcol];
    for (int d8 = 0; d8 < 64; ++d8) {
        uint4 raw = *(const uint4*)(sr + d8 * 8);
        const float* wr = &sWc[lcol][d8 * 8];
        s = fmaf(bflo(raw.x), wr[0], s); s = fmaf(bfhi(raw.x), wr[1], s);
        s = fmaf(bflo(raw.y), wr[2], s); s = fmaf(bfhi(raw.y), wr[3], s);
        s = fmaf(bflo(raw.z), wr[4], s); s = fmaf(bfhi(raw.z), wr[5], s);
        s = fmaf(bflo(raw.w), wr[6], s); s = fmaf(bfhi(raw.w), wr[7], s);
    }
    out[idx] = s;
}

// ============================================================================
extern "C" void kernel_launch(void* const* d_in, const int* in_sizes, int n_in,
                              void* d_out, int out_size, void* d_ws, size_t ws_size,
                              hipStream_t stream) {
    const float* x        = (const float*)d_in[0];
    const float* Wqkv_cls = (const float*)d_in[1];
    const float* bqkv_cls = (const float*)d_in[2];
    const float* Wo_cls   = (const float*)d_in[3];
    const float* bo_cls   = (const float*)d_in[4];
    const float* Wqkv_loc = (const float*)d_in[5];
    const float* bqkv_loc = (const float*)d_in[6];
    const float* Wo_loc   = (const float*)d_in[7];
    const float* bo_loc   = (const float*)d_in[8];
    const float* logn     = (const float*)d_in[9];
    const float* Wqkv_h   = (const float*)d_in[10];
    const float* bqkv_h   = (const float*)d_in[11];
    const float* Wo_h     = (const float*)d_in[12];
    const float* bo_h     = (const float*)d_in[13];
    const float* Wqkv_v   = (const float*)d_in[14];
    const float* bqkv_v   = (const float*)d_in[15];
    const float* Wo_v     = (const float*)d_in[16];
    const float* bo_v     = (const float*)d_in[17];
    const float* W1       = (const float*)d_in[18];
    const float* b1       = (const float*)d_in[19];
    const float* W2       = (const float*)d_in[20];
    const float* b2       = (const float*)d_in[21];
    const float* Wc       = (const float*)d_in[22];
    const float* bc       = (const float*)d_in[23];
    float* out = (float*)d_out;

    // workspace layout in bf16 (unsigned short) elements; ~161 MB total
    unsigned short* wsu = (unsigned short*)d_ws;
    unsigned short* xb        = wsu;                 //  4,194,304
    unsigned short* qkvA      = wsu +  4194304;      // [B,S,2560] 20,971,520
    unsigned short* qkvB      = wsu + 25165824;      // [B,S,3072] 25,165,824
    unsigned short* attnout_h = wsu + 50331648;      //  4,194,304
    unsigned short* attnout_v = wsu + 54525952;      //  4,194,304
    unsigned short* attended  = wsu + 58720256;      //  4,194,304
    unsigned short* combined  = wsu + 62914560;      //  8,388,608
    unsigned short* hidden    = wsu + 71303168;      //  4,194,304
    unsigned short* seq       = attended;            // reuse (free after qkvB GEMM)
    unsigned short* WqkvT_cls = wsu + 75497472;      //    786,432 each (contig!)
    unsigned short* WqkvT_loc = wsu + 76283904;
    unsigned short* WqkvT_h   = wsu + 77070336;
    unsigned short* WqkvT_v   = wsu + 77856768;
    unsigned short* WoT_loc   = wsu + 78643200;      //    262,144 each (contig!)
    unsigned short* WoT_h     = wsu + 78905344;
    unsigned short* WoT_v     = wsu + 79167488;
    unsigned short* W2T       = wsu + 79429632;
    unsigned short* W1T       = wsu + 79691776;      //    524,288
    unsigned short* WoT_cls   = wsu + 80216064;      //    262,144
    float* q_cls              = (float*)(wsu + 80478208);   // 1024
    float* gpre               = q_cls + 1024;               // 1024
    float* part               = gpre + 1024;                // 16*CCH*66

    const int NSP_NONE = 1 << 30;
    dim3 blk(256);

    // --- conversions (3 wtrans launches) ---
    cvt_kernel<<<dim3(2048), blk, 0, stream>>>(x, xb, 524288);
    wtrans_kernel<<<dim3(48, 16, 4), blk, 0, stream>>>(
        Wqkv_cls, Wqkv_loc, Wqkv_h, Wqkv_v, Wqkv_cls,
        WqkvT_cls, WqkvT_loc, WqkvT_h, WqkvT_v, WqkvT_cls, 512, 1536);
    wtrans_kernel<<<dim3(16, 16, 5), blk, 0, stream>>>(
        Wo_loc, Wo_h, Wo_v, W2, Wo_cls,
        WoT_loc, WoT_h, WoT_v, W2T, WoT_cls, 512, 512);
    wtrans_kernel<<<dim3(16, 32, 1), blk, 0, stream>>>(
        W1, W1, W1, W1, W1,
        W1T, W1T, W1T, W1T, W1T, 1024, 512);

    // --- fused cls-KV + loc-QKV GEMM: N=2560 -> qkvA [clsK|clsV|locQ|locK|locV]
    mgemm_kernel<128, 0><<<dim3(20, 64), blk, 0, stream>>>(
        xb, 512, WqkvT_cls + 512 * 512, 512,
        bqkv_cls + 512, bqkv_loc, 1024, qkvA, 2560, 512, 0, 0, 0);

    // --- cls path ---
    qcls_kernel<<<dim3(256), blk, 0, stream>>>(xb, WqkvT_cls, bqkv_cls, q_cls);
    cls_attn_part<<<dim3(16, CCH), blk, 0, stream>>>(q_cls, qkvA, part);
    cls_attn_reduce<<<dim3(16), dim3(64), 0, stream>>>(part, gpre);

    // --- loc attention (qkvA cols 1024..2559) ---
    wattn_kernel<<<dim3(64, 8, 2), blk, 0, stream>>>(
        qkvA, 2560, 1024, attnout_h, 0, 1);
    mgemm_kernel<64, 0><<<dim3(4, 128), blk, 0, stream>>>(
        attnout_h, 512, WoT_loc, 512, bo_loc, bo_loc, NSP_NONE,
        attended, 512, 512, 0, 0, 0);
    clsproj_kernel<<<dim3(256), blk, 0, stream>>>(gpre, WoT_cls, bo_cls, logn, attended);

    // --- fused h+v QKV GEMM: N=3072 -> qkvB [hQ|hK|hV|vQ|vK|vV] ---
    mgemm_kernel<128, 0><<<dim3(24, 64), blk, 0, stream>>>(
        attended, 512, WqkvT_h, 512,
        bqkv_h, bqkv_v, 1536, qkvB, 3072, 512, 0, 0, 0);

    // --- fused h+v windowed attention (z = branch*2 + batch) ---
    wattn_kernel<<<dim3(64, 8, 4), blk, 0, stream>>>(
        qkvB, 3072, 0, attnout_h, 4194304, 0);

    // --- fused dual Wo projection: z selects {attnout, WoT, bias, C-cols} ---
    mgemm_kernel<64, 0><<<dim3(4, 128, 2), blk, 0, stream>>>(
        attnout_h, 512, WoT_h, 512, bo_h, bo_v, NSP_NONE,
        combined, 1024, 512, 4194304, 262144, 512);

    // --- MLP + classifier ---
    mgemm_kernel<64, 1><<<dim3(4, 128), blk, 0, stream>>>(
        combined, 1024, W1T, 1024, b1, b1, NSP_NONE, hidden, 512, 1024, 0, 0, 0);
    mgemm_kernel<64, 0><<<dim3(4, 128), blk, 0, stream>>>(
        hidden, 512, W2T, 512, b2, b2, NSP_NONE, seq, 512, 512, 0, 0, 0);
    logits_kernel<<<dim3((M_ * 17 + 255) / 256), blk, 0, stream>>>(seq, Wc, bc, out);
}

// Round 11
// 329.824 us; speedup vs baseline: 4.8243x; 1.0200x over previous
//
#include <hip/hip_runtime.h>

#define S_ 4096
#define H_ 512
#define M_ 8192
#define CCH 8   // cls-attention key chunks (512 keys each)

typedef __attribute__((ext_vector_type(8))) short s16x8;   // 8 bf16 = 4 VGPR
typedef __attribute__((ext_vector_type(4))) float f32x4;   // MFMA acc frag

__device__ __forceinline__ float bflo(unsigned int w) { return __uint_as_float(w << 16); }
__device__ __forceinline__ float bfhi(unsigned int w) { return __uint_as_float(w & 0xFFFF0000u); }
__device__ __forceinline__ float bf2f(unsigned short u) { return __uint_as_float(((unsigned int)u) << 16); }
__device__ __forceinline__ unsigned short f2bf(float f) {   // RNE
    unsigned int x = __float_as_uint(f);
    return (unsigned short)((x + 0x7FFFu + ((x >> 16) & 1u)) >> 16);
}
__device__ __forceinline__ void gload_lds16(const void* g, void* l) {
    __builtin_amdgcn_global_load_lds(
        (const __attribute__((address_space(1))) unsigned int*)g,
        (__attribute__((address_space(3))) unsigned int*)l, 16, 0, 0);
}

// ============================================================================
// fp32 -> bf16 cast (x input), 8 elts/thread.  n8 = total_elements / 8.
// ============================================================================
__global__ __launch_bounds__(256) void cvt_kernel(
    const float* __restrict__ in, unsigned short* __restrict__ out, int n8)
{
    int i = blockIdx.x * 256 + threadIdx.x;
    if (i >= n8) return;
    float4 a = *(const float4*)(in + (size_t)i * 8);
    float4 b = *(const float4*)(in + (size_t)i * 8 + 4);
    uint4 pk;
    pk.x = (unsigned int)f2bf(a.x) | ((unsigned int)f2bf(a.y) << 16);
    pk.y = (unsigned int)f2bf(a.z) | ((unsigned int)f2bf(a.w) << 16);
    pk.z = (unsigned int)f2bf(b.x) | ((unsigned int)f2bf(b.y) << 16);
    pk.w = (unsigned int)f2bf(b.z) | ((unsigned int)f2bf(b.w) << 16);
    *(uint4*)(out + (size_t)i * 8) = pk;
}

// ============================================================================
// Weight transpose + cast: fp32 [K][N] -> bf16 [N][K]; up to 5 matrices via z.
// ============================================================================
__global__ __launch_bounds__(256) void wtrans_kernel(
    const float* __restrict__ p0, const float* __restrict__ p1,
    const float* __restrict__ p2, const float* __restrict__ p3,
    const float* __restrict__ p4,
    unsigned short* o0, unsigned short* o1,
    unsigned short* o2, unsigned short* o3, unsigned short* o4,
    int K, int N)
{
    const float* in; unsigned short* out;
    switch (blockIdx.z) {
        case 0:  in = p0; out = o0; break;
        case 1:  in = p1; out = o1; break;
        case 2:  in = p2; out = o2; break;
        case 3:  in = p3; out = o3; break;
        default: in = p4; out = o4; break;
    }
    __shared__ float tile[32][33];
    int n0 = blockIdx.x * 32, k0 = blockIdx.y * 32;
    int tx = threadIdx.x & 31, ty = threadIdx.x >> 5;   // 32 x 8
    #pragma unroll
    for (int i = 0; i < 4; ++i) {
        int k = k0 + ty * 4 + i;
        tile[ty * 4 + i][tx] = in[(size_t)k * N + n0 + tx];
    }
    __syncthreads();
    #pragma unroll
    for (int i = 0; i < 4; ++i) {
        int n = n0 + ty * 4 + i;
        out[(size_t)n * K + k0 + tx] = f2bf(tile[tx][ty * 4 + i]);
    }
}

// ============================================================================
// bf16 MFMA GEMM (inner loop hardware-verified, unchanged).
// (a) column-split bias; (b) dual-z launches (az/bz/cz offsets, biasB for z>0)
// ============================================================================
template<int BM, int RELU>
__global__ __launch_bounds__(256) void mgemm_kernel(
    const unsigned short* __restrict__ A, int lda,
    const unsigned short* __restrict__ Bt, int ldb,
    const float* __restrict__ bias, const float* __restrict__ biasB, int nsplit,
    unsigned short* __restrict__ C, int ldc, int K,
    size_t az, size_t bz, size_t cz)
{
    constexpr int MF = BM / 32;
    constexpr int ASEG = BM / 32;
    __shared__ __align__(16) unsigned short As[BM * 64];
    __shared__ __align__(16) unsigned short Bs[128 * 64];
    const int z = blockIdx.z;
    A  += (size_t)z * az;
    Bt += (size_t)z * bz;
    C  += (size_t)z * cz;
    if (z > 0) bias = biasB;
    const int t = threadIdx.x;
    const int w = t >> 6, l = t & 63;
    const int wr = w >> 1, wc = w & 1;
    const int row0 = blockIdx.y * BM, col0 = blockIdx.x * 128;
    const int lr = l >> 3;
    const int lc = l & 7;

    f32x4 acc[MF][4];
    #pragma unroll
    for (int i = 0; i < MF; ++i)
        #pragma unroll
        for (int j = 0; j < 4; ++j) acc[i][j] = {0.f, 0.f, 0.f, 0.f};

    for (int k0 = 0; k0 < K; k0 += 64) {
        __syncthreads();
        #pragma unroll
        for (int i = 0; i < ASEG; ++i) {
            int seg = w * ASEG + i;
            int r = seg * 8 + lr;
            int kc = lc ^ (r & 7);
            gload_lds16(A + (size_t)(row0 + r) * lda + k0 + kc * 8,
                        (void*)(As + seg * 512));
        }
        #pragma unroll
        for (int i = 0; i < 4; ++i) {
            int seg = w * 4 + i;
            int r = seg * 8 + lr;
            int kc = lc ^ (r & 7);
            gload_lds16(Bt + (size_t)(col0 + r) * ldb + k0 + kc * 8,
                        (void*)(Bs + seg * 512));
        }
        __syncthreads();

        s16x8 af[MF][2], bf[4][2];
        #pragma unroll
        for (int mf = 0; mf < MF; ++mf)
            #pragma unroll
            for (int kk = 0; kk < 2; ++kk) {
                int r = wr * (BM / 2) + mf * 16 + (l & 15);
                int ch = (kk * 4 + (l >> 4)) ^ (r & 7);
                af[mf][kk] = *(const s16x8*)(As + r * 64 + ch * 8);
            }
        #pragma unroll
        for (int nf = 0; nf < 4; ++nf)
            #pragma unroll
            for (int kk = 0; kk < 2; ++kk) {
                int r = wc * 64 + nf * 16 + (l & 15);
                int ch = (kk * 4 + (l >> 4)) ^ (r & 7);
                bf[nf][kk] = *(const s16x8*)(Bs + r * 64 + ch * 8);
            }
        #pragma unroll
        for (int kk = 0; kk < 2; ++kk)
            #pragma unroll
            for (int mf = 0; mf < MF; ++mf)
                #pragma unroll
                for (int nf = 0; nf < 4; ++nf)
                    acc[mf][nf] = __builtin_amdgcn_mfma_f32_16x16x32_bf16(
                        af[mf][kk], bf[nf][kk], acc[mf][nf], 0, 0, 0);
    }

    #pragma unroll
    for (int mf = 0; mf < MF; ++mf)
        #pragma unroll
        for (int nf = 0; nf < 4; ++nf) {
            int col = col0 + wc * 64 + nf * 16 + (l & 15);
            float bb = (col < nsplit) ? bias[col] : biasB[col - nsplit];
            #pragma unroll
            for (int r4 = 0; r4 < 4; ++r4) {
                int row = row0 + wr * (BM / 2) + mf * 16 + (l >> 4) * 4 + r4;
                float v = acc[mf][nf][r4] + bb;
                if (RELU) v = fmaxf(v, 0.f);
                C[(size_t)row * ldc + col] = f2bf(v);
            }
        }
}

// ============================================================================
// Windowed (banded) MHA, MFMA flash version — SWAPPED QK^T softmax.
// mfma(kf, qf): same fragments as before, swapped operands -> S[kpos][q];
// lane l owns q = w*16 + (l&15): 16 scores in-lane, row-reduce = tree +
// shfl_xor(16,32). P packed to Ps[q][kpos] via uint2 (cols l4*4+{0..3}).
// Defer-max (THR=8): skip O-rescale when max stable (algebraic identity).
// XCD-aware n-swizzle: consecutive q-tiles co-locate per XCD for K/V L2 reuse.
// PV, staging, C/D layouts unchanged from the hardware-verified version.
// ============================================================================
__global__ __launch_bounds__(256) void wattn_kernel(
    const unsigned short* __restrict__ qkv, int qld, int qbase,
    unsigned short* __restrict__ out, size_t brstride, int min_key)
{
    const int nb = blockIdx.x;
    const int n = ((nb & 7) << 3) | (nb >> 3);   // XCD swizzle, bijective on 64
    const int h = blockIdx.y;
    const int z = blockIdx.z, br = z >> 1, b = z & 1;
    const int t = threadIdx.x;
    const int w = t >> 6, l = t & 63;
    const int l4 = l >> 4, lm = l & 15;

    __shared__ __align__(16) unsigned short Ks[64 * 64];
    __shared__ __align__(16) unsigned short Vt[64 * 72];
    __shared__ __align__(16) unsigned short Ps[64 * 72];

    const int q0g = n * 64;
    const int qcol = qbase + br * 1536;
    const size_t base = (size_t)b * S_ * qld;
    out += (size_t)br * brstride;

    // Q fragment, pre-scaled by 0.125 (exact exponent shift in bf16 range)
    s16x8 qf[2];
    {
        const unsigned short* qrow =
            qkv + base + (size_t)(q0g + w * 16 + lm) * qld + qcol + h * 64 + l4 * 8;
        qf[0] = *(const s16x8*)(qrow);
        qf[1] = *(const s16x8*)(qrow + 32);
        #pragma unroll
        for (int e = 0; e < 8; ++e) {
            qf[0][e] = (short)f2bf(bf2f((unsigned short)qf[0][e]) * 0.125f);
            qf[1][e] = (short)f2bf(bf2f((unsigned short)qf[1][e]) * 0.125f);
        }
    }

    float m_r = -1e30f, lsum = 0.f;   // per-lane softmax state for q = w*16+lm
    f32x4 oacc[4];                    // O[q_o = w*16+l4*4+r][d = nf*16+lm]
    #pragma unroll
    for (int e = 0; e < 4; ++e) oacc[e] = {0.f, 0.f, 0.f, 0.f};

    const int lr = l >> 3, lc = l & 7;

    for (int c = 0; c < 5; ++c) {
        const int klo = q0g - 128 + c * 64;
        if (klo < 0 || klo >= S_) continue;
        const bool need_mask = (c == 0) | (c == 4) | (klo < min_key);
        __syncthreads();

        // stage K [kpos][d] via global_load_lds, pre-swizzled source
        #pragma unroll
        for (int i = 0; i < 2; ++i) {
            int seg = w * 2 + i;
            int r = seg * 8 + lr;
            int kc = lc ^ (r & 7);
            gload_lds16(qkv + base + (size_t)(klo + r) * qld + qcol + 512 + h * 64 + kc * 8,
                        (void*)(Ks + seg * 512));
        }
        // stage V transposed [d][kpos]
        {
            int jp = (t & 31) * 2, ds = (t >> 5) * 8;
            uint4 r0 = *(const uint4*)(qkv + base + (size_t)(klo + jp) * qld + qcol + 1024 + h * 64 + ds);
            uint4 r1 = *(const uint4*)(qkv + base + (size_t)(klo + jp + 1) * qld + qcol + 1024 + h * 64 + ds);
            const unsigned short* va = (const unsigned short*)&r0;
            const unsigned short* vb = (const unsigned short*)&r1;
            #pragma unroll
            for (int j = 0; j < 8; ++j)
                *(unsigned int*)(Vt + (ds + j) * 72 + jp) =
                    (unsigned int)va[j] | ((unsigned int)vb[j] << 16);
        }
        __syncthreads();

        // --- swapped QK^T: sf[nf][r] = S[kpos = klo + nf*16 + l4*4 + r][q]
        f32x4 sf[4];
        #pragma unroll
        for (int nf = 0; nf < 4; ++nf) sf[nf] = {0.f, 0.f, 0.f, 0.f};
        #pragma unroll
        for (int kk = 0; kk < 2; ++kk)
            #pragma unroll
            for (int nf = 0; nf < 4; ++nf) {
                int r = nf * 16 + lm;
                int ch = (kk * 4 + l4) ^ (r & 7);
                s16x8 kf = *(const s16x8*)(Ks + r * 64 + ch * 8);
                sf[nf] = __builtin_amdgcn_mfma_f32_16x16x32_bf16(kf, qf[kk], sf[nf], 0, 0, 0);
            }

        // --- mask + in-lane max (tree)
        float sv[4][4];
        #pragma unroll
        for (int nf = 0; nf < 4; ++nf)
            #pragma unroll
            for (int r = 0; r < 4; ++r) {
                float xv = sf[nf][r];
                if (need_mask) {
                    int kpos = klo + nf * 16 + l4 * 4 + r;
                    int qpos = q0g + w * 16 + lm;
                    int rel = kpos - qpos;
                    bool valid = (rel <= 128) & (rel >= -128) & (kpos >= min_key);
                    if (!valid) xv = -1e9f;
                }
                sv[nf][r] = xv;
            }
        float mx01 = fmaxf(fmaxf(sv[0][0], sv[0][1]), fmaxf(sv[0][2], sv[0][3]));
        float mx11 = fmaxf(fmaxf(sv[1][0], sv[1][1]), fmaxf(sv[1][2], sv[1][3]));
        float mx21 = fmaxf(fmaxf(sv[2][0], sv[2][1]), fmaxf(sv[2][2], sv[2][3]));
        float mx31 = fmaxf(fmaxf(sv[3][0], sv[3][1]), fmaxf(sv[3][2], sv[3][3]));
        float mx = fmaxf(fmaxf(mx01, mx11), fmaxf(mx21, mx31));
        mx = fmaxf(mx, __shfl_xor(mx, 16, 64));
        mx = fmaxf(mx, __shfl_xor(mx, 32, 64));

        // --- defer-max rescale (THR=8; identity up to rounding)
        if (!__all(mx <= m_r + 8.f)) {
            float mn = fmaxf(m_r, mx);
            float sc = __expf(m_r - mn);
            lsum *= sc;
            m_r = mn;
            float sco[4];
            #pragma unroll
            for (int r4 = 0; r4 < 4; ++r4)
                sco[r4] = __shfl(sc, l4 * 4 + r4, 64);
            #pragma unroll
            for (int nf = 0; nf < 4; ++nf)
                #pragma unroll
                for (int r4 = 0; r4 < 4; ++r4) oacc[nf][r4] *= sco[r4];
        }

        // --- exp + row-sum + packed P store: Ps[q][kpos-local]
        float ps = 0.f;
        #pragma unroll
        for (int nf = 0; nf < 4; ++nf) {
            float p0 = __expf(sv[nf][0] - m_r);
            float p1 = __expf(sv[nf][1] - m_r);
            float p2 = __expf(sv[nf][2] - m_r);
            float p3 = __expf(sv[nf][3] - m_r);
            ps += (p0 + p1) + (p2 + p3);
            uint2 pk;
            pk.x = (unsigned int)f2bf(p0) | ((unsigned int)f2bf(p1) << 16);
            pk.y = (unsigned int)f2bf(p2) | ((unsigned int)f2bf(p3) << 16);
            *(uint2*)(Ps + (w * 16 + lm) * 72 + nf * 16 + l4 * 4) = pk;
        }
        ps += __shfl_xor(ps, 16, 64);
        ps += __shfl_xor(ps, 32, 64);
        lsum += ps;

        // --- PV: O[16q][64d] += P[16q][64k] @ V[64k][64d]  (unchanged)
        #pragma unroll
        for (int kk = 0; kk < 2; ++kk) {
            s16x8 pf = *(const s16x8*)(Ps + (w * 16 + lm) * 72 + l4 * 8 + kk * 32);
            #pragma unroll
            for (int nf = 0; nf < 4; ++nf) {
                s16x8 vf = *(const s16x8*)(Vt + (nf * 16 + lm) * 72 + l4 * 8 + kk * 32);
                oacc[nf] = __builtin_amdgcn_mfma_f32_16x16x32_bf16(pf, vf, oacc[nf], 0, 0, 0);
            }
        }
    }

    // epilogue: redistribute 1/lsum to oacc rows, normalize + bf16 store
    float inv = 1.f / lsum;
    float invo[4];
    #pragma unroll
    for (int r4 = 0; r4 < 4; ++r4)
        invo[r4] = __shfl(inv, l4 * 4 + r4, 64);
    #pragma unroll
    for (int r4 = 0; r4 < 4; ++r4) {
        size_t row = (size_t)b * S_ + q0g + w * 16 + l4 * 4 + r4;
        #pragma unroll
        for (int nf = 0; nf < 4; ++nf)
            out[row * 512 + h * 64 + nf * 16 + lm] = f2bf(oacc[nf][r4] * invo[r4]);
    }
}

// ============================================================================
// cls q projection, wave-per-output (verified).
// ============================================================================
__global__ __launch_bounds__(256) void qcls_kernel(
    const unsigned short* __restrict__ xb, const unsigned short* __restrict__ WqkvT,
    const float* __restrict__ bqkv, float* __restrict__ q_cls)
{
    int gw = blockIdx.x * 4 + (threadIdx.x >> 6);   // 0..1023
    int l = threadIdx.x & 63;
    int b = gw >> 9, j = gw & 511;
    s16x8 xv = *(const s16x8*)(xb + (size_t)b * S_ * H_ + l * 8);
    s16x8 wv = *(const s16x8*)(WqkvT + (size_t)j * 512 + l * 8);
    float s = 0.f;
    #pragma unroll
    for (int e = 0; e < 8; ++e)
        s += bf2f((unsigned short)xv[e]) * bf2f((unsigned short)wv[e]);
    #pragma unroll
    for (int st = 1; st < 64; st <<= 1) s += __shfl_xor(s, st, 64);
    if (l == 0) q_cls[gw] = s + bqkv[j];
}

// ============================================================================
// cls attention flash-split part (verified): reads qkvA (ld 2560, K col 0,
// V col 512). part[(bh*CCH+ck)*66] = {o_c[0..63], m_c, l_c}
// ============================================================================
__global__ __launch_bounds__(256) void cls_attn_part(
    const float* __restrict__ q_cls, const unsigned short* __restrict__ qkv,
    float* __restrict__ part)
{
    const int bh = blockIdx.x, ck = blockIdx.y;
    const int b = bh >> 3, h = bh & 7;
    const int t = threadIdx.x;
    __shared__ float sQ[64];
    __shared__ float sP[512];
    __shared__ float red[256];
    __shared__ float pacc[16][64];
    if (t < 64) sQ[t] = q_cls[b * H_ + h * 64 + t] * 0.125f;
    __syncthreads();
    const size_t base = (size_t)b * S_ * 2560;
    const int j0 = ck * 512;

    float sv[2], smax = -1e30f;
    #pragma unroll
    for (int i = 0; i < 2; ++i) {
        int j = j0 + t + i * 256;
        const unsigned short* kr = qkv + base + (size_t)j * 2560 + h * 64;
        float s = 0.f;
        #pragma unroll
        for (int d8 = 0; d8 < 8; ++d8) {
            uint4 raw = *(const uint4*)(kr + d8 * 8);
            const float* q = &sQ[d8 * 8];
            s = fmaf(q[0], bflo(raw.x), s); s = fmaf(q[1], bfhi(raw.x), s);
            s = fmaf(q[2], bflo(raw.y), s); s = fmaf(q[3], bfhi(raw.y), s);
            s = fmaf(q[4], bflo(raw.z), s); s = fmaf(q[5], bfhi(raw.z), s);
            s = fmaf(q[6], bflo(raw.w), s); s = fmaf(q[7], bfhi(raw.w), s);
        }
        sv[i] = s;
        smax = fmaxf(smax, s);
    }
    red[t] = smax; __syncthreads();
    for (int st = 128; st > 0; st >>= 1) {
        if (t < st) red[t] = fmaxf(red[t], red[t + st]);
        __syncthreads();
    }
    float mc = red[0];
    __syncthreads();
    float ls = 0.f;
    #pragma unroll
    for (int i = 0; i < 2; ++i) {
        float p = __expf(sv[i] - mc);
        sP[t + i * 256] = p;
        ls += p;
    }
    red[t] = ls; __syncthreads();
    for (int st = 128; st > 0; st >>= 1) {
        if (t < st) red[t] += red[t + st];
        __syncthreads();
    }
    float lc = red[0];

    int g = t >> 4, d4 = t & 15;
    float4 acc; acc.x = 0.f; acc.y = 0.f; acc.z = 0.f; acc.w = 0.f;
    for (int j = g * 32; j < g * 32 + 32; ++j) {
        float p = sP[j];
        uint2 raw = *(const uint2*)(qkv + base + (size_t)(j0 + j) * 2560 + 512 + h * 64 + d4 * 4);
        acc.x = fmaf(p, bflo(raw.x), acc.x); acc.y = fmaf(p, bfhi(raw.x), acc.y);
        acc.z = fmaf(p, bflo(raw.y), acc.z); acc.w = fmaf(p, bfhi(raw.y), acc.w);
    }
    *(float4*)&pacc[g][d4 * 4] = acc;
    __syncthreads();
    float* op = part + (size_t)(bh * CCH + ck) * 66;
    if (t < 64) {
        float r = 0.f;
        #pragma unroll
        for (int g2 = 0; g2 < 16; ++g2) r += pacc[g2][t];
        op[t] = r;
    }
    if (t == 64) op[64] = mc;
    if (t == 65) op[65] = lc;
}

// ============================================================================
// cls attention reduce (verified): merge CCH chunks -> gpre[b,512] fp32
// ============================================================================
__global__ __launch_bounds__(64) void cls_attn_reduce(
    const float* __restrict__ part, float* __restrict__ gpre)
{
    int bh = blockIdx.x, t = threadIdx.x;
    int b = bh >> 3, h = bh & 7;
    const float* pp = part + (size_t)bh * CCH * 66;
    float M = -1e30f;
    #pragma unroll
    for (int c = 0; c < CCH; ++c) M = fmaxf(M, pp[c * 66 + 64]);
    float L = 0.f, o = 0.f;
    #pragma unroll
    for (int c = 0; c < CCH; ++c) {
        float wgt = __expf(pp[c * 66 + 64] - M);
        L += pp[c * 66 + 65] * wgt;
        o += pp[c * 66 + t] * wgt;
    }
    gpre[b * H_ + h * 64 + t] = o / L;
}

// ============================================================================
// cls Wo projection + LogN, wave-per-output (verified)
// ============================================================================
__global__ __launch_bounds__(256) void clsproj_kernel(
    const float* __restrict__ gpre, const unsigned short* __restrict__ WoT,
    const float* __restrict__ bo, const float* __restrict__ logn,
    unsigned short* __restrict__ attended)
{
    int gw = blockIdx.x * 4 + (threadIdx.x >> 6);
    int l = threadIdx.x & 63;
    int b = gw >> 9, j = gw & 511;
    const float* gr = gpre + b * H_ + l * 8;
    s16x8 wv = *(const s16x8*)(WoT + (size_t)j * 512 + l * 8);
    float s = 0.f;
    #pragma unroll
    for (int e = 0; e < 8; ++e) s += gr[e] * bf2f((unsigned short)wv[e]);
    #pragma unroll
    for (int st = 1; st < 64; st <<= 1) s += __shfl_xor(s, st, 64);
    if (l == 0) attended[(size_t)b * S_ * H_ + j] = f2bf((s + bo[j]) * logn[0]);
}

// ============================================================================
// classifier (verified): out[r,l] = seq[r,:] @ Wc[:,l] + bc[l]
// ============================================================================
__global__ __launch_bounds__(256) void logits_kernel(
    const unsigned short* __restrict__ seq, const float* __restrict__ Wc,
    const float* __restrict__ bc, float* __restrict__ out)
{
    __shared__ float sWc[17][516];
    for (int i = threadIdx.x; i < 512 * 17; i += 256) {
        int d = i / 17, lcol = i % 17;
        sWc[lcol][d] = Wc[i];
    }
    __syncthreads();
    int idx = blockIdx.x * 256 + threadIdx.x;
    if (idx >= M_ * 17) return;
    int r = idx / 17, lcol = idx % 17;
    const unsigned short* sr = seq + (size_t)r * H_;
    float s = bc[lcol];
    for (int d8 = 0; d8 < 64; ++d8) {
        uint4 raw = *(const uint4*)(sr + d8 * 8);
        const float* wr = &sWc[lcol][d8 * 8];
        s = fmaf(bflo(raw.x), wr[0], s); s = fmaf(bfhi(raw.x), wr[1], s);
        s = fmaf(bflo(raw.y), wr[2], s); s = fmaf(bfhi(raw.y), wr[3], s);
        s = fmaf(bflo(raw.z), wr[4], s); s = fmaf(bfhi(raw.z), wr[5], s);
        s = fmaf(bflo(raw.w), wr[6], s); s = fmaf(bfhi(raw.w), wr[7], s);
    }
    out[idx] = s;
}

// ============================================================================
extern "C" void kernel_launch(void* const* d_in, const int* in_sizes, int n_in,
                              void* d_out, int out_size, void* d_ws, size_t ws_size,
                              hipStream_t stream) {
    const float* x        = (const float*)d_in[0];
    const float* Wqkv_cls = (const float*)d_in[1];
    const float* bqkv_cls = (const float*)d_in[2];
    const float* Wo_cls   = (const float*)d_in[3];
    const float* bo_cls   = (const float*)d_in[4];
    const float* Wqkv_loc = (const float*)d_in[5];
    const float* bqkv_loc = (const float*)d_in[6];
    const float* Wo_loc   = (const float*)d_in[7];
    const float* bo_loc   = (const float*)d_in[8];
    const float* logn     = (const float*)d_in[9];
    const float* Wqkv_h   = (const float*)d_in[10];
    const float* bqkv_h   = (const float*)d_in[11];
    const float* Wo_h     = (const float*)d_in[12];
    const float* bo_h     = (const float*)d_in[13];
    const float* Wqkv_v   = (const float*)d_in[14];
    const float* bqkv_v   = (const float*)d_in[15];
    const float* Wo_v     = (const float*)d_in[16];
    const float* bo_v     = (const float*)d_in[17];
    const float* W1       = (const float*)d_in[18];
    const float* b1       = (const float*)d_in[19];
    const float* W2       = (const float*)d_in[20];
    const float* b2       = (const float*)d_in[21];
    const float* Wc       = (const float*)d_in[22];
    const float* bc       = (const float*)d_in[23];
    float* out = (float*)d_out;

    // workspace layout in bf16 (unsigned short) elements; ~161 MB total
    unsigned short* wsu = (unsigned short*)d_ws;
    unsigned short* xb        = wsu;                 //  4,194,304
    unsigned short* qkvA      = wsu +  4194304;      // [B,S,2560] 20,971,520
    unsigned short* qkvB      = wsu + 25165824;      // [B,S,3072] 25,165,824
    unsigned short* attnout_h = wsu + 50331648;      //  4,194,304
    unsigned short* attnout_v = wsu + 54525952;      //  4,194,304
    unsigned short* attended  = wsu + 58720256;      //  4,194,304
    unsigned short* combined  = wsu + 62914560;      //  8,388,608
    unsigned short* hidden    = wsu + 71303168;      //  4,194,304
    unsigned short* seq       = attended;            // reuse (free after qkvB GEMM)
    unsigned short* WqkvT_cls = wsu + 75497472;      //    786,432 each (contig!)
    unsigned short* WqkvT_loc = wsu + 76283904;
    unsigned short* WqkvT_h   = wsu + 77070336;
    unsigned short* WqkvT_v   = wsu + 77856768;
    unsigned short* WoT_loc   = wsu + 78643200;      //    262,144 each (contig!)
    unsigned short* WoT_h     = wsu + 78905344;
    unsigned short* WoT_v     = wsu + 79167488;
    unsigned short* W2T       = wsu + 79429632;
    unsigned short* W1T       = wsu + 79691776;      //    524,288
    unsigned short* WoT_cls   = wsu + 80216064;      //    262,144
    float* q_cls              = (float*)(wsu + 80478208);   // 1024
    float* gpre               = q_cls + 1024;               // 1024
    float* part               = gpre + 1024;                // 16*CCH*66

    const int NSP_NONE = 1 << 30;
    dim3 blk(256);

    // --- conversions ---
    cvt_kernel<<<dim3(2048), blk, 0, stream>>>(x, xb, 524288);
    wtrans_kernel<<<dim3(48, 16, 4), blk, 0, stream>>>(
        Wqkv_cls, Wqkv_loc, Wqkv_h, Wqkv_v, Wqkv_cls,
        WqkvT_cls, WqkvT_loc, WqkvT_h, WqkvT_v, WqkvT_cls, 512, 1536);
    wtrans_kernel<<<dim3(16, 16, 5), blk, 0, stream>>>(
        Wo_loc, Wo_h, Wo_v, W2, Wo_cls,
        WoT_loc, WoT_h, WoT_v, W2T, WoT_cls, 512, 512);
    wtrans_kernel<<<dim3(16, 32, 1), blk, 0, stream>>>(
        W1, W1, W1, W1, W1,
        W1T, W1T, W1T, W1T, W1T, 1024, 512);

    // --- fused cls-KV + loc-QKV GEMM: N=2560 -> qkvA [clsK|clsV|locQ|locK|locV]
    mgemm_kernel<128, 0><<<dim3(20, 64), blk, 0, stream>>>(
        xb, 512, WqkvT_cls + 512 * 512, 512,
        bqkv_cls + 512, bqkv_loc, 1024, qkvA, 2560, 512, 0, 0, 0);

    // --- cls path ---
    qcls_kernel<<<dim3(256), blk, 0, stream>>>(xb, WqkvT_cls, bqkv_cls, q_cls);
    cls_attn_part<<<dim3(16, CCH), blk, 0, stream>>>(q_cls, qkvA, part);
    cls_attn_reduce<<<dim3(16), dim3(64), 0, stream>>>(part, gpre);

    // --- loc attention (qkvA cols 1024..2559) ---
    wattn_kernel<<<dim3(64, 8, 2), blk, 0, stream>>>(
        qkvA, 2560, 1024, attnout_h, 0, 1);
    mgemm_kernel<64, 0><<<dim3(4, 128), blk, 0, stream>>>(
        attnout_h, 512, WoT_loc, 512, bo_loc, bo_loc, NSP_NONE,
        attended, 512, 512, 0, 0, 0);
    clsproj_kernel<<<dim3(256), blk, 0, stream>>>(gpre, WoT_cls, bo_cls, logn, attended);

    // --- fused h+v QKV GEMM: N=3072 -> qkvB [hQ|hK|hV|vQ|vK|vV] ---
    mgemm_kernel<128, 0><<<dim3(24, 64), blk, 0, stream>>>(
        attended, 512, WqkvT_h, 512,
        bqkv_h, bqkv_v, 1536, qkvB, 3072, 512, 0, 0, 0);

    // --- fused h+v windowed attention (z = branch*2 + batch) ---
    wattn_kernel<<<dim3(64, 8, 4), blk, 0, stream>>>(
        qkvB, 3072, 0, attnout_h, 4194304, 0);

    // --- fused dual Wo projection ---
    mgemm_kernel<64, 0><<<dim3(4, 128, 2), blk, 0, stream>>>(
        attnout_h, 512, WoT_h, 512, bo_h, bo_v, NSP_NONE,
        combined, 1024, 512, 4194304, 262144, 512);

    // --- MLP + classifier ---
    mgemm_kernel<64, 1><<<dim3(4, 128), blk, 0, stream>>>(
        combined, 1024, W1T, 1024, b1, b1, NSP_NONE, hidden, 512, 1024, 0, 0, 0);
    mgemm_kernel<64, 0><<<dim3(4, 128), blk, 0, stream>>>(
        hidden, 512, W2T, 512, b2, b2, NSP_NONE, seq, 512, 512, 0, 0, 0);
    logits_kernel<<<dim3((M_ * 17 + 255) / 256), blk, 0, stream>>>(seq, Wc, bc, out);
}